// Round 1
// baseline (1017.476 us; speedup 1.0000x reference)
//
#include <hip/hip_runtime.h>
#include <hip/hip_bf16.h>
#include <cstdint>

// ---------------------------------------------------------------------------
// GABlock: grid-attn (C/2) + shifted-window attn (C/4) + window attn (C/4)
//          -> concat -> fc + cLN + residual -> MLP(gelu) + cLN -> final sum
// fp32 everywhere (round 0: correctness-first).
// ---------------------------------------------------------------------------

#define HW_ 128
#define PIMG 16384            // 128*128 pixels per image
#define BSTRX 2097152L        // 128 ch * 16384 px

// ---------------- small setup: dynamic position bias MLP -------------------
__global__ void pos_mlp_k(const float* __restrict__ w1, const float* __restrict__ b1,
                          const float* __restrict__ w2, const float* __restrict__ b2,
                          const float* __restrict__ w3, const float* __restrict__ b3,
                          float* __restrict__ table) {
  int j = blockIdx.x * 256 + threadIdx.x;
  if (j >= 961) return;
  float chv = (float)(j / 31) - 15.0f;
  float cwv = (float)(j % 31) - 15.0f;
  float t1[16], t2[16];
#pragma unroll
  for (int i = 0; i < 16; ++i) {
    float s = fmaf(w1[i * 2], chv, fmaf(w1[i * 2 + 1], cwv, b1[i]));
    t1[i] = fmaxf(s, 0.0f);
  }
#pragma unroll
  for (int i = 0; i < 16; ++i) {
    float s = b2[i];
#pragma unroll
    for (int k = 0; k < 16; ++k) s = fmaf(w2[i * 16 + k], t1[k], s);
    t2[i] = fmaxf(s, 0.0f);
  }
#pragma unroll
  for (int hh = 0; hh < 4; ++hh) {
    float s = b3[hh];
#pragma unroll
    for (int k = 0; k < 16; ++k) s = fmaf(w3[hh * 16 + k], t2[k], s);
    table[j * 4 + hh] = s;
  }
}

__global__ void pbias_gather_k(const float* __restrict__ table, float* __restrict__ pbias) {
  int t = blockIdx.x * 256 + threadIdx.x;      // 4*256*256 = 262144 total
  int hh = t >> 16;
  int r = t & 65535;
  int n = r >> 8;
  int m = r & 255;
  int idx = ((n >> 4) - (m >> 4) + 15) * 31 + ((n & 15) - (m & 15) + 15);
  pbias[t] = table[idx * 4 + hh];
}

// ---------------- generic tiled conv1x1 (fp32 GEMM) ------------------------
// out[co, p] = sum_ci W[co,ci] * in[ci, p] + B[co]
// block: 256 thr, tile 64 co x 64 px, thread micro-tile 4x4, K chunks of 16.
// OMODE 0: normal (bz = batch)   out[bz*obstr + co*ocstr + p]
// OMODE 1: grid-shuffle output   (bz = image b, p = pixel)   -> [gb, co, n]
// OMODE 2: grid-unshuffle output (bz = gb, p = n)            -> [b, co, h, w]
template <int CIN, int ACT, int OMODE>
__global__ __launch_bounds__(256) void conv1x1_k(
    const float* __restrict__ in, long in_bstr, int in_cstr,
    const float* __restrict__ W, const float* __restrict__ Bv,
    float* __restrict__ out, long out_bstr, int out_cstr) {
  __shared__ float Ws[16][64];
  __shared__ float Is[16][64];
  const int tid = threadIdx.x;
  const int p0 = blockIdx.x * 64;
  const int co0 = blockIdx.y * 64;
  const int bz = blockIdx.z;
  const int tpx = (tid & 15) * 4;
  const int tco = (tid >> 4) * 4;
  float acc[4][4];
#pragma unroll
  for (int i = 0; i < 4; ++i)
#pragma unroll
    for (int j = 0; j < 4; ++j) acc[i][j] = 0.0f;

  const float* inb = in + (long)bz * in_bstr + p0;
  const float* Wb = W + (long)co0 * CIN;

  for (int k0 = 0; k0 < CIN; k0 += 16) {
#pragma unroll
    for (int i = 0; i < 4; ++i) {
      int l = tid + 256 * i;
      int k = l >> 6, c = l & 63;
      Ws[k][c] = Wb[(long)c * CIN + k0 + k];
    }
#pragma unroll
    for (int i = 0; i < 4; ++i) {
      int l = tid + 256 * i;
      int k = l >> 6, px = l & 63;
      Is[k][px] = inb[(long)(k0 + k) * in_cstr + px];
    }
    __syncthreads();
#pragma unroll
    for (int k = 0; k < 16; ++k) {
      float av[4], bv4[4];
#pragma unroll
      for (int j = 0; j < 4; ++j) av[j] = Is[k][tpx + j];
#pragma unroll
      for (int i = 0; i < 4; ++i) bv4[i] = Ws[k][tco + i];
#pragma unroll
      for (int i = 0; i < 4; ++i)
#pragma unroll
        for (int j = 0; j < 4; ++j) acc[i][j] = fmaf(bv4[i], av[j], acc[i][j]);
    }
    __syncthreads();
  }

#pragma unroll
  for (int i = 0; i < 4; ++i) {
    int co = co0 + tco + i;
    float bv = Bv[co];
#pragma unroll
    for (int j = 0; j < 4; ++j) {
      float v = acc[i][j] + bv;
      if (ACT == 1) v = 0.5f * v * (1.0f + erff(v * 0.7071067811865475f));
      int p = p0 + tpx + j;
      long oidx;
      if (OMODE == 0) {
        oidx = (long)bz * out_bstr + (long)co * out_cstr + p;
      } else if (OMODE == 1) {
        int hh = p >> 7, ww_ = p & 127;
        int gb = bz * 64 + (hh & 7) * 8 + (ww_ & 7);
        int n = (hh >> 3) * 16 + (ww_ >> 3);
        oidx = (long)gb * out_bstr + (long)co * 256 + n;
      } else {
        int b = bz >> 6, ih = (bz >> 3) & 7, iw = bz & 7;
        int hh = (p >> 4) * 8 + ih, ww_ = (p & 15) * 8 + iw;
        oidx = (long)b * out_bstr + (long)co * out_cstr + hh * 128 + ww_;
      }
      out[oidx] = v;
    }
  }
}

// ---------------- grid attention (N=256 tokens, hd=16) ---------------------
// blocks (gb=256, h=4); 256 threads = one per query token.
// buffers are [gb][64][256] channel-major; head h occupies channels h*16..h*16+15.
__global__ __launch_bounds__(256) void grid_attn_k(
    const float* __restrict__ Qb, const float* __restrict__ Kb,
    const float* __restrict__ Vb, long qstr, long kstr, long vstr,
    const float* __restrict__ pbias, float* __restrict__ outb, long ostr) {
  __shared__ float Ks[16][256];
  __shared__ float Vs[16][256];
  const int gb = blockIdx.x, h = blockIdx.y, tid = threadIdx.x;
  const float* Kp = Kb + (long)gb * kstr + h * 4096;
  const float* Vp = Vb + (long)gb * vstr + h * 4096;
#pragma unroll
  for (int d = 0; d < 16; ++d) {
    Ks[d][tid] = Kp[d * 256 + tid];
    Vs[d][tid] = Vp[d * 256 + tid];
  }
  const float* Qp = Qb + (long)gb * qstr + h * 4096;
  float q[16];
#pragma unroll
  for (int d = 0; d < 16; ++d) q[d] = Qp[d * 256 + tid] * 0.25f;
  __syncthreads();

  const float* bp = pbias + ((long)(h << 8) + tid) * 256;  // [h][n][m]
  float mrun = -1e30f, lrun = 0.0f;
  float acc[16];
#pragma unroll
  for (int d = 0; d < 16; ++d) acc[d] = 0.0f;

#pragma unroll 2
  for (int m = 0; m < 256; ++m) {
    float s = bp[m];
#pragma unroll
    for (int d = 0; d < 16; ++d) s = fmaf(q[d], Ks[d][m], s);
    if (s > mrun) {
      float cc = __expf(mrun - s);
      lrun *= cc;
#pragma unroll
      for (int d = 0; d < 16; ++d) acc[d] *= cc;
      mrun = s;
    }
    float p = __expf(s - mrun);
    lrun += p;
#pragma unroll
    for (int d = 0; d < 16; ++d) acc[d] = fmaf(p, Vs[d][m], acc[d]);
  }
  float inv = 1.0f / lrun;
  float* op = outb + (long)gb * ostr + h * 4096;
#pragma unroll
  for (int d = 0; d < 16; ++d) op[d * 256 + tid] = acc[d] * inv;
}

// ---------------- fused swin window attention ------------------------------
// one block per window (1024 windows), 256 threads.
// 32 channels, 4 heads x hd=8, 64 tokens; everything in LDS.
__global__ __launch_bounds__(256) void swin_k(
    const float* __restrict__ x, int c0, int shift,
    const float* __restrict__ qkvw, const float* __restrict__ qkvb,
    const float* __restrict__ rpb, const float* __restrict__ pw,
    const float* __restrict__ pb, float* __restrict__ y, int yc0) {
  __shared__ float xt[64][33];      // token-major input window
  __shared__ float qkvs[96][64];    // channel-major q/k/v
  __shared__ float rps[900];        // 225 x 4 relative-pos bias
  __shared__ float ao[64][33];      // attention output, token-major
  const int wb = blockIdx.x;
  const int b = wb >> 8;
  const int wrem = wb & 255;
  const int wh = wrem >> 4, ww = wrem & 15;
  const int tid = threadIdx.x;

  for (int i = tid; i < 900; i += 256) rps[i] = rpb[i];
  {
    int c = tid >> 3, r = tid & 7;
    int hsrc = (wh * 8 + r + shift) & 127;
    const float* xrow = x + (((long)(b * 128 + c0 + c)) << 14) + (hsrc << 7);
#pragma unroll
    for (int cc = 0; cc < 8; ++cc) {
      int wsrc = (ww * 8 + cc + shift) & 127;
      xt[r * 8 + cc][c] = xrow[wsrc];
    }
  }
  __syncthreads();
  {  // qkv projection: 96 x 64
    int n = tid & 63, cg = tid >> 6;
    for (int co = cg; co < 96; co += 4) {
      float s = qkvb[co];
      const float* wr = qkvw + co * 32;
#pragma unroll
      for (int ci = 0; ci < 32; ++ci) s = fmaf(wr[ci], xt[n][ci], s);
      qkvs[co][n] = s;
    }
  }
  __syncthreads();
  {  // attention: thread = (head, query token)
    const int h = tid >> 6, n = tid & 63;
    float q[8];
#pragma unroll
    for (int d = 0; d < 8; ++d) q[d] = qkvs[h * 8 + d][n] * 0.35355339059327373f;
    const int rn = n >> 3, cn = n & 7;
    int regn = 0;
    if (shift > 0) {
      int hr = wh * 8 + rn, wr_ = ww * 8 + cn;
      int rh = hr < 120 ? 0 : (hr < 124 ? 1 : 2);
      int rw = wr_ < 120 ? 0 : (wr_ < 124 ? 1 : 2);
      regn = rh * 3 + rw;
    }
    float s[64];
#pragma unroll
    for (int m = 0; m < 64; ++m) {
      float v = 0.0f;
#pragma unroll
      for (int d = 0; d < 8; ++d) v = fmaf(q[d], qkvs[32 + h * 8 + d][m], v);
      int rm = m >> 3, cm = m & 7;
      v += rps[((rn - rm + 7) * 15 + (cn - cm + 7)) * 4 + h];
      if (shift > 0) {
        int hr = wh * 8 + rm, wr_ = ww * 8 + cm;
        int rh = hr < 120 ? 0 : (hr < 124 ? 1 : 2);
        int rw = wr_ < 120 ? 0 : (wr_ < 124 ? 1 : 2);
        if (rh * 3 + rw != regn) v -= 100.0f;
      }
      s[m] = v;
    }
    float mx = -1e30f;
#pragma unroll
    for (int m = 0; m < 64; ++m) mx = fmaxf(mx, s[m]);
    float l = 0.0f;
#pragma unroll
    for (int m = 0; m < 64; ++m) {
      float p = __expf(s[m] - mx);
      s[m] = p;
      l += p;
    }
    float inv = 1.0f / l;
    float o[8];
#pragma unroll
    for (int d = 0; d < 8; ++d) o[d] = 0.0f;
#pragma unroll
    for (int m = 0; m < 64; ++m) {
      float p = s[m];
#pragma unroll
      for (int d = 0; d < 8; ++d) o[d] = fmaf(p, qkvs[64 + h * 8 + d][m], o[d]);
    }
#pragma unroll
    for (int d = 0; d < 8; ++d) ao[n][h * 8 + d] = o[d] * inv;
  }
  __syncthreads();
  {  // output projection + un-window + roll-back
    int nn = tid & 63, cg = tid >> 6;
    int rr = nn >> 3, cc = nn & 7;
    int hdst = (wh * 8 + rr + shift) & 127;
    int wdst = (ww * 8 + cc + shift) & 127;
    long obase = (((long)(b * 128 + yc0)) << 14) + (hdst << 7) + wdst;
    for (int co = cg; co < 32; co += 4) {
      float s = pb[co];
      const float* wr = pw + co * 32;
#pragma unroll
      for (int ci = 0; ci < 32; ++ci) s = fmaf(wr[ci], ao[nn][ci], s);
      y[obase + ((long)co << 14)] = s;
    }
  }
}

// ---------------- conv1x1 (Cout=128 in-block) + channel-LN + residual ------
// FINAL=0:  out = cln(conv(in)) + xorig            (fc stage -> x2)
// FINAL=1:  out = cln(conv(in)) + xorig + x2in     (m2 stage -> final)
template <int CIN, int FINAL>
__global__ __launch_bounds__(256) void conv_cln_k(
    const float* __restrict__ in, long in_bstr,
    const float* __restrict__ W, const float* __restrict__ Bv,
    const float* __restrict__ g, const float* __restrict__ bet,
    const float* __restrict__ xorig, const float* __restrict__ x2in,
    float* __restrict__ out) {
  __shared__ float Ws[16][128];
  __shared__ float Is[16][32];
  __shared__ float redS[32][32];
  __shared__ float redQ[32][32];
  __shared__ float muA[32], rsA[32];
  const int tid = threadIdx.x;
  const int p0 = blockIdx.x * 32;
  const int b = blockIdx.z;
  const int tpx = (tid & 7) * 4;
  const int tco = (tid >> 3) * 4;
  float acc[4][4];
#pragma unroll
  for (int i = 0; i < 4; ++i)
#pragma unroll
    for (int j = 0; j < 4; ++j) acc[i][j] = 0.0f;

  const float* inb = in + (long)b * in_bstr + p0;
  for (int k0 = 0; k0 < CIN; k0 += 16) {
#pragma unroll
    for (int i = 0; i < 8; ++i) {
      int l = tid + 256 * i;
      int k = l >> 7, c = l & 127;
      Ws[k][c] = W[(long)c * CIN + k0 + k];
    }
#pragma unroll
    for (int i = 0; i < 2; ++i) {
      int l = tid + 256 * i;
      int k = l >> 5, px = l & 31;
      Is[k][px] = inb[(long)(k0 + k) * PIMG + px];
    }
    __syncthreads();
#pragma unroll
    for (int k = 0; k < 16; ++k) {
      float av[4], bv4[4];
#pragma unroll
      for (int j = 0; j < 4; ++j) av[j] = Is[k][tpx + j];
#pragma unroll
      for (int i = 0; i < 4; ++i) bv4[i] = Ws[k][tco + i];
#pragma unroll
      for (int i = 0; i < 4; ++i)
#pragma unroll
        for (int j = 0; j < 4; ++j) acc[i][j] = fmaf(bv4[i], av[j], acc[i][j]);
    }
    __syncthreads();
  }
#pragma unroll
  for (int i = 0; i < 4; ++i) {
    float bv = Bv[tco + i];
#pragma unroll
    for (int j = 0; j < 4; ++j) acc[i][j] += bv;
  }
  // channel LN: reduce over 128 channels per pixel
  const int cog = tid >> 3;
#pragma unroll
  for (int j = 0; j < 4; ++j) {
    float s = acc[0][j] + acc[1][j] + acc[2][j] + acc[3][j];
    float qq = acc[0][j] * acc[0][j] + acc[1][j] * acc[1][j] +
               acc[2][j] * acc[2][j] + acc[3][j] * acc[3][j];
    redS[cog][tpx + j] = s;
    redQ[cog][tpx + j] = qq;
  }
  __syncthreads();
  if (tid < 32) {
    float s = 0.0f, qq = 0.0f;
    for (int cg = 0; cg < 32; ++cg) {
      s += redS[cg][tid];
      qq += redQ[cg][tid];
    }
    float mu = s * (1.0f / 128.0f);
    float var = qq * (1.0f / 128.0f) - mu * mu;
    muA[tid] = mu;
    rsA[tid] = rsqrtf(var + 1e-5f);
  }
  __syncthreads();
#pragma unroll
  for (int i = 0; i < 4; ++i) {
    int co = tco + i;
    float gg = g[co], bb = bet[co];
#pragma unroll
    for (int j = 0; j < 4; ++j) {
      int px = tpx + j;
      float v = (acc[i][j] - muA[px]) * rsA[px] * gg + bb;
      long idx = (long)b * BSTRX + (long)co * PIMG + p0 + px;
      float res = v + xorig[idx];
      if (FINAL) res += x2in[idx];
      out[idx] = res;
    }
  }
}

// ---------------------------------------------------------------------------
extern "C" void kernel_launch(void* const* d_in, const int* in_sizes, int n_in,
                              void* d_out, int out_size, void* d_ws, size_t ws_size,
                              hipStream_t stream) {
  (void)in_sizes; (void)n_in; (void)out_size; (void)ws_size;
  const float* x        = (const float*)d_in[0];
  const float* ln_g     = (const float*)d_in[1];
  const float* ln_b     = (const float*)d_in[2];
  const float* ga_qkv_w = (const float*)d_in[3];
  const float* ga_qkv_b = (const float*)d_in[4];
  const float* ga_gp_w  = (const float*)d_in[5];
  const float* ga_gp_b  = (const float*)d_in[6];
  const float* pos_w1   = (const float*)d_in[7];
  const float* pos_b1   = (const float*)d_in[8];
  const float* pos_w2   = (const float*)d_in[9];
  const float* pos_b2   = (const float*)d_in[10];
  const float* pos_w3   = (const float*)d_in[11];
  const float* pos_b3   = (const float*)d_in[12];
  const float* a1_pw    = (const float*)d_in[13];
  const float* a1_pb    = (const float*)d_in[14];
  const float* a2_pw    = (const float*)d_in[15];
  const float* a2_pb    = (const float*)d_in[16];
  const float* sw_qkv_w = (const float*)d_in[17];
  const float* sw_qkv_b = (const float*)d_in[18];
  const float* sw_rpb   = (const float*)d_in[19];
  const float* sw_pw    = (const float*)d_in[20];
  const float* sw_pb    = (const float*)d_in[21];
  const float* wn_qkv_w = (const float*)d_in[22];
  const float* wn_qkv_b = (const float*)d_in[23];
  const float* wn_rpb   = (const float*)d_in[24];
  const float* wn_pw    = (const float*)d_in[25];
  const float* wn_pb    = (const float*)d_in[26];
  const float* fc_w     = (const float*)d_in[27];
  const float* fc_b     = (const float*)d_in[28];
  const float* n2_g     = (const float*)d_in[29];
  const float* n2_b     = (const float*)d_in[30];
  const float* m1_w     = (const float*)d_in[31];
  const float* m1_b     = (const float*)d_in[32];
  const float* m2_w     = (const float*)d_in[33];
  const float* m2_b     = (const float*)d_in[34];
  float* out = (float*)d_out;
  float* ws = (float*)d_ws;

  // workspace layout (floats), with lifetime-based aliasing:
  float* qkvg  = ws;                 // [256 gb][192][256]  = 12,582,912
  float* xgrid = ws + 12582912;      // [256][64][256]      =  4,194,304
  float* t1    = ws + 16777216;      // [256][64][256] (reused as t2)
  float* t1p   = ws + 20971520;      // [256][64][256]
  float* ybuf  = ws;                 // [4][128][16384] alias over dead qkvg
  float* hbuf  = ws;                 // [4][256][16384] alias (y dead by m1)
  float* pbias = ws + 25165824;      // [4][256][256]       =    262,144
  float* ptab  = ws + 25427968;      // 961*4
  float* x2    = ws + 25432064;      // [4][128][16384]     =  8,388,608

  // --- dynamic position bias ---
  pos_mlp_k<<<4, 256, 0, stream>>>(pos_w1, pos_b1, pos_w2, pos_b2, pos_w3, pos_b3, ptab);
  pbias_gather_k<<<1024, 256, 0, stream>>>(ptab, pbias);

  // --- grid branch: qkv conv + gp conv (outputs grid-shuffled) ---
  conv1x1_k<64, 0, 1><<<dim3(256, 3, 4), 256, 0, stream>>>(
      x, BSTRX, PIMG, ga_qkv_w, ga_qkv_b, qkvg, 49152L, 0);
  conv1x1_k<64, 0, 1><<<dim3(256, 1, 4), 256, 0, stream>>>(
      x, BSTRX, PIMG, ga_gp_w, ga_gp_b, xgrid, 16384L, 0);

  // attn1: Q=xgrid, K=qkv.k, V=qkv.v -> t1 ; proj a1 -> t1p
  grid_attn_k<<<dim3(256, 4), 256, 0, stream>>>(
      xgrid, qkvg + 16384, qkvg + 32768, 16384L, 49152L, 49152L, pbias, t1, 16384L);
  conv1x1_k<64, 0, 0><<<dim3(4, 1, 256), 256, 0, stream>>>(
      t1, 16384L, 256, a1_pw, a1_pb, t1p, 16384L, 256);

  // attn2: Q=qkv.q, K=xgrid, V=t1p -> t2(=t1 buf) ; proj a2 -> y[ch 64..127]
  grid_attn_k<<<dim3(256, 4), 256, 0, stream>>>(
      qkvg, xgrid, t1p, 49152L, 16384L, 16384L, pbias, t1, 16384L);
  conv1x1_k<64, 0, 2><<<dim3(4, 1, 256), 256, 0, stream>>>(
      t1, 16384L, 256, a2_pw, a2_pb, ybuf + 64L * PIMG, BSTRX, PIMG);

  // --- window branches -> y[ch 0..31] (plain), y[ch 32..63] (shifted) ---
  swin_k<<<1024, 256, 0, stream>>>(x, 96, 0, wn_qkv_w, wn_qkv_b, wn_rpb, wn_pw, wn_pb, ybuf, 0);
  swin_k<<<1024, 256, 0, stream>>>(x, 64, 4, sw_qkv_w, sw_qkv_b, sw_rpb, sw_pw, sw_pb, ybuf, 32);

  // --- fc + cLN + residual -> x2 ---
  conv_cln_k<128, 0><<<dim3(512, 1, 4), 256, 0, stream>>>(
      ybuf, BSTRX, fc_w, fc_b, ln_g, ln_b, x, nullptr, x2);

  // --- MLP: m1 (gelu) -> h ; m2 + cLN + final sum -> out ---
  conv1x1_k<128, 1, 0><<<dim3(256, 4, 4), 256, 0, stream>>>(
      x2, BSTRX, PIMG, m1_w, m1_b, hbuf, 4194304L, PIMG);
  conv_cln_k<256, 1><<<dim3(512, 1, 4), 256, 0, stream>>>(
      hbuf, 4194304L, m2_w, m2_b, n2_g, n2_b, x, x2, out);
}

// Round 2
// 718.966 us; speedup vs baseline: 1.4152x; 1.4152x over previous
//
#include <hip/hip_runtime.h>
#include <hip/hip_bf16.h>
#include <cstdint>

// ---------------------------------------------------------------------------
// GABlock: grid-attn (C/2) + shifted-window attn (C/4) + window attn (C/4)
//          -> concat -> fc + cLN + residual -> MLP(gelu) + cLN -> final sum
// R2: grid attention rewritten with chunked scores + float4 LDS reads.
// ---------------------------------------------------------------------------

#define HW_ 128
#define PIMG 16384            // 128*128 pixels per image
#define BSTRX 2097152L        // 128 ch * 16384 px

// ---------------- small setup: dynamic position bias MLP -------------------
__global__ void pos_mlp_k(const float* __restrict__ w1, const float* __restrict__ b1,
                          const float* __restrict__ w2, const float* __restrict__ b2,
                          const float* __restrict__ w3, const float* __restrict__ b3,
                          float* __restrict__ table) {
  int j = blockIdx.x * 256 + threadIdx.x;
  if (j >= 961) return;
  float chv = (float)(j / 31) - 15.0f;
  float cwv = (float)(j % 31) - 15.0f;
  float t1[16], t2[16];
#pragma unroll
  for (int i = 0; i < 16; ++i) {
    float s = fmaf(w1[i * 2], chv, fmaf(w1[i * 2 + 1], cwv, b1[i]));
    t1[i] = fmaxf(s, 0.0f);
  }
#pragma unroll
  for (int i = 0; i < 16; ++i) {
    float s = b2[i];
#pragma unroll
    for (int k = 0; k < 16; ++k) s = fmaf(w2[i * 16 + k], t1[k], s);
    t2[i] = fmaxf(s, 0.0f);
  }
#pragma unroll
  for (int hh = 0; hh < 4; ++hh) {
    float s = b3[hh];
#pragma unroll
    for (int k = 0; k < 16; ++k) s = fmaf(w3[hh * 16 + k], t2[k], s);
    table[j * 4 + hh] = s;
  }
}

__global__ void pbias_gather_k(const float* __restrict__ table, float* __restrict__ pbias) {
  int t = blockIdx.x * 256 + threadIdx.x;      // 4*256*256 = 262144 total
  int hh = t >> 16;
  int r = t & 65535;
  int n = r >> 8;
  int m = r & 255;
  int idx = ((n >> 4) - (m >> 4) + 15) * 31 + ((n & 15) - (m & 15) + 15);
  pbias[t] = table[idx * 4 + hh];
}

// ---------------- generic tiled conv1x1 (fp32 GEMM) ------------------------
template <int CIN, int ACT, int OMODE>
__global__ __launch_bounds__(256) void conv1x1_k(
    const float* __restrict__ in, long in_bstr, int in_cstr,
    const float* __restrict__ W, const float* __restrict__ Bv,
    float* __restrict__ out, long out_bstr, int out_cstr) {
  __shared__ float Ws[16][64];
  __shared__ float Is[16][64];
  const int tid = threadIdx.x;
  const int p0 = blockIdx.x * 64;
  const int co0 = blockIdx.y * 64;
  const int bz = blockIdx.z;
  const int tpx = (tid & 15) * 4;
  const int tco = (tid >> 4) * 4;
  float acc[4][4];
#pragma unroll
  for (int i = 0; i < 4; ++i)
#pragma unroll
    for (int j = 0; j < 4; ++j) acc[i][j] = 0.0f;

  const float* inb = in + (long)bz * in_bstr + p0;
  const float* Wb = W + (long)co0 * CIN;

  for (int k0 = 0; k0 < CIN; k0 += 16) {
#pragma unroll
    for (int i = 0; i < 4; ++i) {
      int l = tid + 256 * i;
      int k = l >> 6, c = l & 63;
      Ws[k][c] = Wb[(long)c * CIN + k0 + k];
    }
#pragma unroll
    for (int i = 0; i < 4; ++i) {
      int l = tid + 256 * i;
      int k = l >> 6, px = l & 63;
      Is[k][px] = inb[(long)(k0 + k) * in_cstr + px];
    }
    __syncthreads();
#pragma unroll
    for (int k = 0; k < 16; ++k) {
      float av[4], bv4[4];
#pragma unroll
      for (int j = 0; j < 4; ++j) av[j] = Is[k][tpx + j];
#pragma unroll
      for (int i = 0; i < 4; ++i) bv4[i] = Ws[k][tco + i];
#pragma unroll
      for (int i = 0; i < 4; ++i)
#pragma unroll
        for (int j = 0; j < 4; ++j) acc[i][j] = fmaf(bv4[i], av[j], acc[i][j]);
    }
    __syncthreads();
  }

#pragma unroll
  for (int i = 0; i < 4; ++i) {
    int co = co0 + tco + i;
    float bv = Bv[co];
#pragma unroll
    for (int j = 0; j < 4; ++j) {
      float v = acc[i][j] + bv;
      if (ACT == 1) v = 0.5f * v * (1.0f + erff(v * 0.7071067811865475f));
      int p = p0 + tpx + j;
      long oidx;
      if (OMODE == 0) {
        oidx = (long)bz * out_bstr + (long)co * out_cstr + p;
      } else if (OMODE == 1) {
        int hh = p >> 7, ww_ = p & 127;
        int gb = bz * 64 + (hh & 7) * 8 + (ww_ & 7);
        int n = (hh >> 3) * 16 + (ww_ >> 3);
        oidx = (long)gb * out_bstr + (long)co * 256 + n;
      } else {
        int b = bz >> 6, ih = (bz >> 3) & 7, iw = bz & 7;
        int hh = (p >> 4) * 8 + ih, ww_ = (p & 15) * 8 + iw;
        oidx = (long)b * out_bstr + (long)co * out_cstr + hh * 128 + ww_;
      }
      out[oidx] = v;
    }
  }
}

// ---------------- grid attention (N=256 tokens, hd=16) ---------------------
// blocks (gb=256, h=4); 256 threads = one query token per thread.
// Chunked (32-key) online softmax; float4 broadcast LDS reads.
__global__ __launch_bounds__(256) void grid_attn_k(
    const float* __restrict__ Qb, const float* __restrict__ Kb,
    const float* __restrict__ Vb, long qstr, long kstr, long vstr,
    const float* __restrict__ pbias, float* __restrict__ outb, long ostr) {
  __shared__ float Ks[16][256];
  __shared__ float Vs[16][256];
  const int gb = blockIdx.x, h = blockIdx.y, tid = threadIdx.x;
  const float* Kp = Kb + (long)gb * kstr + h * 4096;
  const float* Vp = Vb + (long)gb * vstr + h * 4096;
#pragma unroll
  for (int d = 0; d < 16; ++d) {
    Ks[d][tid] = Kp[d * 256 + tid];
    Vs[d][tid] = Vp[d * 256 + tid];
  }
  const float* Qp = Qb + (long)gb * qstr + h * 4096;
  float q[16];
#pragma unroll
  for (int d = 0; d < 16; ++d) q[d] = Qp[d * 256 + tid] * 0.25f;
  __syncthreads();

  const float* bp = pbias + ((long)(h << 8) + tid) * 256;  // [h][n][m]
  float mrun = -1e30f, lrun = 0.0f;
  float acc[16];
#pragma unroll
  for (int d = 0; d < 16; ++d) acc[d] = 0.0f;

  for (int m0 = 0; m0 < 256; m0 += 32) {
    float s[32];
#pragma unroll
    for (int i = 0; i < 8; ++i) {
      float4 bv = *(const float4*)&bp[m0 + 4 * i];
      s[4 * i] = bv.x; s[4 * i + 1] = bv.y; s[4 * i + 2] = bv.z; s[4 * i + 3] = bv.w;
    }
    // scores: 32 independent 16-deep fmaf chains, b128 broadcast LDS reads
#pragma unroll
    for (int d = 0; d < 16; ++d) {
      float qd = q[d];
#pragma unroll
      for (int i = 0; i < 8; ++i) {
        float4 kv = *(const float4*)&Ks[d][m0 + 4 * i];
        s[4 * i]     = fmaf(qd, kv.x, s[4 * i]);
        s[4 * i + 1] = fmaf(qd, kv.y, s[4 * i + 1]);
        s[4 * i + 2] = fmaf(qd, kv.z, s[4 * i + 2]);
        s[4 * i + 3] = fmaf(qd, kv.w, s[4 * i + 3]);
      }
    }
    float mx = s[0];
#pragma unroll
    for (int i = 1; i < 32; ++i) mx = fmaxf(mx, s[i]);
    if (mx > mrun) {
      float cc = __expf(mrun - mx);
      lrun *= cc;
#pragma unroll
      for (int d = 0; d < 16; ++d) acc[d] *= cc;
      mrun = mx;
    }
    float ls = 0.0f;
#pragma unroll
    for (int i = 0; i < 32; ++i) {
      s[i] = __expf(s[i] - mrun);
      ls += s[i];
    }
    lrun += ls;
    // PV: 16 independent 32-deep dot-product chains
#pragma unroll
    for (int d = 0; d < 16; ++d) {
      float a = acc[d];
#pragma unroll
      for (int i = 0; i < 8; ++i) {
        float4 vv = *(const float4*)&Vs[d][m0 + 4 * i];
        a = fmaf(s[4 * i],     vv.x, a);
        a = fmaf(s[4 * i + 1], vv.y, a);
        a = fmaf(s[4 * i + 2], vv.z, a);
        a = fmaf(s[4 * i + 3], vv.w, a);
      }
      acc[d] = a;
    }
  }
  float inv = 1.0f / lrun;
  float* op = outb + (long)gb * ostr + h * 4096;
#pragma unroll
  for (int d = 0; d < 16; ++d) op[d * 256 + tid] = acc[d] * inv;
}

// ---------------- fused swin window attention ------------------------------
__global__ __launch_bounds__(256) void swin_k(
    const float* __restrict__ x, int c0, int shift,
    const float* __restrict__ qkvw, const float* __restrict__ qkvb,
    const float* __restrict__ rpb, const float* __restrict__ pw,
    const float* __restrict__ pb, float* __restrict__ y, int yc0) {
  __shared__ float xt[64][33];      // token-major input window
  __shared__ float qkvs[96][64];    // channel-major q/k/v
  __shared__ float rps[900];        // 225 x 4 relative-pos bias
  __shared__ float ao[64][33];      // attention output, token-major
  const int wb = blockIdx.x;
  const int b = wb >> 8;
  const int wrem = wb & 255;
  const int wh = wrem >> 4, ww = wrem & 15;
  const int tid = threadIdx.x;

  for (int i = tid; i < 900; i += 256) rps[i] = rpb[i];
  {
    int c = tid >> 3, r = tid & 7;
    int hsrc = (wh * 8 + r + shift) & 127;
    const float* xrow = x + (((long)(b * 128 + c0 + c)) << 14) + (hsrc << 7);
#pragma unroll
    for (int cc = 0; cc < 8; ++cc) {
      int wsrc = (ww * 8 + cc + shift) & 127;
      xt[r * 8 + cc][c] = xrow[wsrc];
    }
  }
  __syncthreads();
  {  // qkv projection: 96 x 64
    int n = tid & 63, cg = tid >> 6;
    for (int co = cg; co < 96; co += 4) {
      float s = qkvb[co];
      const float* wr = qkvw + co * 32;
#pragma unroll
      for (int ci = 0; ci < 32; ++ci) s = fmaf(wr[ci], xt[n][ci], s);
      qkvs[co][n] = s;
    }
  }
  __syncthreads();
  {  // attention: thread = (head, query token)
    const int h = tid >> 6, n = tid & 63;
    float q[8];
#pragma unroll
    for (int d = 0; d < 8; ++d) q[d] = qkvs[h * 8 + d][n] * 0.35355339059327373f;
    const int rn = n >> 3, cn = n & 7;
    int regn = 0;
    if (shift > 0) {
      int hr = wh * 8 + rn, wr_ = ww * 8 + cn;
      int rh = hr < 120 ? 0 : (hr < 124 ? 1 : 2);
      int rw = wr_ < 120 ? 0 : (wr_ < 124 ? 1 : 2);
      regn = rh * 3 + rw;
    }
    float s[64];
#pragma unroll
    for (int m = 0; m < 64; ++m) {
      float v = 0.0f;
#pragma unroll
      for (int d = 0; d < 8; ++d) v = fmaf(q[d], qkvs[32 + h * 8 + d][m], v);
      int rm = m >> 3, cm = m & 7;
      v += rps[((rn - rm + 7) * 15 + (cn - cm + 7)) * 4 + h];
      if (shift > 0) {
        int hr = wh * 8 + rm, wr_ = ww * 8 + cm;
        int rh = hr < 120 ? 0 : (hr < 124 ? 1 : 2);
        int rw = wr_ < 120 ? 0 : (wr_ < 124 ? 1 : 2);
        if (rh * 3 + rw != regn) v -= 100.0f;
      }
      s[m] = v;
    }
    float mx = -1e30f;
#pragma unroll
    for (int m = 0; m < 64; ++m) mx = fmaxf(mx, s[m]);
    float l = 0.0f;
#pragma unroll
    for (int m = 0; m < 64; ++m) {
      float p = __expf(s[m] - mx);
      s[m] = p;
      l += p;
    }
    float inv = 1.0f / l;
    float o[8];
#pragma unroll
    for (int d = 0; d < 8; ++d) o[d] = 0.0f;
#pragma unroll
    for (int m = 0; m < 64; ++m) {
      float p = s[m];
#pragma unroll
      for (int d = 0; d < 8; ++d) o[d] = fmaf(p, qkvs[64 + h * 8 + d][m], o[d]);
    }
#pragma unroll
    for (int d = 0; d < 8; ++d) ao[n][h * 8 + d] = o[d] * inv;
  }
  __syncthreads();
  {  // output projection + un-window + roll-back
    int nn = tid & 63, cg = tid >> 6;
    int rr = nn >> 3, cc = nn & 7;
    int hdst = (wh * 8 + rr + shift) & 127;
    int wdst = (ww * 8 + cc + shift) & 127;
    long obase = (((long)(b * 128 + yc0)) << 14) + (hdst << 7) + wdst;
    for (int co = cg; co < 32; co += 4) {
      float s = pb[co];
      const float* wr = pw + co * 32;
#pragma unroll
      for (int ci = 0; ci < 32; ++ci) s = fmaf(wr[ci], ao[nn][ci], s);
      y[obase + ((long)co << 14)] = s;
    }
  }
}

// ---------------- conv1x1 (Cout=128 in-block) + channel-LN + residual ------
template <int CIN, int FINAL>
__global__ __launch_bounds__(256) void conv_cln_k(
    const float* __restrict__ in, long in_bstr,
    const float* __restrict__ W, const float* __restrict__ Bv,
    const float* __restrict__ g, const float* __restrict__ bet,
    const float* __restrict__ xorig, const float* __restrict__ x2in,
    float* __restrict__ out) {
  __shared__ float Ws[16][128];
  __shared__ float Is[16][32];
  __shared__ float redS[32][32];
  __shared__ float redQ[32][32];
  __shared__ float muA[32], rsA[32];
  const int tid = threadIdx.x;
  const int p0 = blockIdx.x * 32;
  const int b = blockIdx.z;
  const int tpx = (tid & 7) * 4;
  const int tco = (tid >> 3) * 4;
  float acc[4][4];
#pragma unroll
  for (int i = 0; i < 4; ++i)
#pragma unroll
    for (int j = 0; j < 4; ++j) acc[i][j] = 0.0f;

  const float* inb = in + (long)b * in_bstr + p0;
  for (int k0 = 0; k0 < CIN; k0 += 16) {
#pragma unroll
    for (int i = 0; i < 8; ++i) {
      int l = tid + 256 * i;
      int k = l >> 7, c = l & 127;
      Ws[k][c] = W[(long)c * CIN + k0 + k];
    }
#pragma unroll
    for (int i = 0; i < 2; ++i) {
      int l = tid + 256 * i;
      int k = l >> 5, px = l & 31;
      Is[k][px] = inb[(long)(k0 + k) * PIMG + px];
    }
    __syncthreads();
#pragma unroll
    for (int k = 0; k < 16; ++k) {
      float av[4], bv4[4];
#pragma unroll
      for (int j = 0; j < 4; ++j) av[j] = Is[k][tpx + j];
#pragma unroll
      for (int i = 0; i < 4; ++i) bv4[i] = Ws[k][tco + i];
#pragma unroll
      for (int i = 0; i < 4; ++i)
#pragma unroll
        for (int j = 0; j < 4; ++j) acc[i][j] = fmaf(bv4[i], av[j], acc[i][j]);
    }
    __syncthreads();
  }
#pragma unroll
  for (int i = 0; i < 4; ++i) {
    float bv = Bv[tco + i];
#pragma unroll
    for (int j = 0; j < 4; ++j) acc[i][j] += bv;
  }
  const int cog = tid >> 3;
#pragma unroll
  for (int j = 0; j < 4; ++j) {
    float s = acc[0][j] + acc[1][j] + acc[2][j] + acc[3][j];
    float qq = acc[0][j] * acc[0][j] + acc[1][j] * acc[1][j] +
               acc[2][j] * acc[2][j] + acc[3][j] * acc[3][j];
    redS[cog][tpx + j] = s;
    redQ[cog][tpx + j] = qq;
  }
  __syncthreads();
  if (tid < 32) {
    float s = 0.0f, qq = 0.0f;
    for (int cg = 0; cg < 32; ++cg) {
      s += redS[cg][tid];
      qq += redQ[cg][tid];
    }
    float mu = s * (1.0f / 128.0f);
    float var = qq * (1.0f / 128.0f) - mu * mu;
    muA[tid] = mu;
    rsA[tid] = rsqrtf(var + 1e-5f);
  }
  __syncthreads();
#pragma unroll
  for (int i = 0; i < 4; ++i) {
    int co = tco + i;
    float gg = g[co], bb = bet[co];
#pragma unroll
    for (int j = 0; j < 4; ++j) {
      int px = tpx + j;
      float v = (acc[i][j] - muA[px]) * rsA[px] * gg + bb;
      long idx = (long)b * BSTRX + (long)co * PIMG + p0 + px;
      float res = v + xorig[idx];
      if (FINAL) res += x2in[idx];
      out[idx] = res;
    }
  }
}

// ---------------------------------------------------------------------------
extern "C" void kernel_launch(void* const* d_in, const int* in_sizes, int n_in,
                              void* d_out, int out_size, void* d_ws, size_t ws_size,
                              hipStream_t stream) {
  (void)in_sizes; (void)n_in; (void)out_size; (void)ws_size;
  const float* x        = (const float*)d_in[0];
  const float* ln_g     = (const float*)d_in[1];
  const float* ln_b     = (const float*)d_in[2];
  const float* ga_qkv_w = (const float*)d_in[3];
  const float* ga_qkv_b = (const float*)d_in[4];
  const float* ga_gp_w  = (const float*)d_in[5];
  const float* ga_gp_b  = (const float*)d_in[6];
  const float* pos_w1   = (const float*)d_in[7];
  const float* pos_b1   = (const float*)d_in[8];
  const float* pos_w2   = (const float*)d_in[9];
  const float* pos_b2   = (const float*)d_in[10];
  const float* pos_w3   = (const float*)d_in[11];
  const float* pos_b3   = (const float*)d_in[12];
  const float* a1_pw    = (const float*)d_in[13];
  const float* a1_pb    = (const float*)d_in[14];
  const float* a2_pw    = (const float*)d_in[15];
  const float* a2_pb    = (const float*)d_in[16];
  const float* sw_qkv_w = (const float*)d_in[17];
  const float* sw_qkv_b = (const float*)d_in[18];
  const float* sw_rpb   = (const float*)d_in[19];
  const float* sw_pw    = (const float*)d_in[20];
  const float* sw_pb    = (const float*)d_in[21];
  const float* wn_qkv_w = (const float*)d_in[22];
  const float* wn_qkv_b = (const float*)d_in[23];
  const float* wn_rpb   = (const float*)d_in[24];
  const float* wn_pw    = (const float*)d_in[25];
  const float* wn_pb    = (const float*)d_in[26];
  const float* fc_w     = (const float*)d_in[27];
  const float* fc_b     = (const float*)d_in[28];
  const float* n2_g     = (const float*)d_in[29];
  const float* n2_b     = (const float*)d_in[30];
  const float* m1_w     = (const float*)d_in[31];
  const float* m1_b     = (const float*)d_in[32];
  const float* m2_w     = (const float*)d_in[33];
  const float* m2_b     = (const float*)d_in[34];
  float* out = (float*)d_out;
  float* ws = (float*)d_ws;

  float* qkvg  = ws;                 // [256 gb][192][256]
  float* xgrid = ws + 12582912;      // [256][64][256]
  float* t1    = ws + 16777216;      // [256][64][256] (reused as t2)
  float* t1p   = ws + 20971520;      // [256][64][256]
  float* ybuf  = ws;                 // [4][128][16384] alias over dead qkvg
  float* hbuf  = ws;                 // [4][256][16384] alias (y dead by m1)
  float* pbias = ws + 25165824;      // [4][256][256]
  float* ptab  = ws + 25427968;      // 961*4
  float* x2    = ws + 25432064;      // [4][128][16384]

  pos_mlp_k<<<4, 256, 0, stream>>>(pos_w1, pos_b1, pos_w2, pos_b2, pos_w3, pos_b3, ptab);
  pbias_gather_k<<<1024, 256, 0, stream>>>(ptab, pbias);

  conv1x1_k<64, 0, 1><<<dim3(256, 3, 4), 256, 0, stream>>>(
      x, BSTRX, PIMG, ga_qkv_w, ga_qkv_b, qkvg, 49152L, 0);
  conv1x1_k<64, 0, 1><<<dim3(256, 1, 4), 256, 0, stream>>>(
      x, BSTRX, PIMG, ga_gp_w, ga_gp_b, xgrid, 16384L, 0);

  grid_attn_k<<<dim3(256, 4), 256, 0, stream>>>(
      xgrid, qkvg + 16384, qkvg + 32768, 16384L, 49152L, 49152L, pbias, t1, 16384L);
  conv1x1_k<64, 0, 0><<<dim3(4, 1, 256), 256, 0, stream>>>(
      t1, 16384L, 256, a1_pw, a1_pb, t1p, 16384L, 256);

  grid_attn_k<<<dim3(256, 4), 256, 0, stream>>>(
      qkvg, xgrid, t1p, 49152L, 16384L, 16384L, pbias, t1, 16384L);
  conv1x1_k<64, 0, 2><<<dim3(4, 1, 256), 256, 0, stream>>>(
      t1, 16384L, 256, a2_pw, a2_pb, ybuf + 64L * PIMG, BSTRX, PIMG);

  swin_k<<<1024, 256, 0, stream>>>(x, 96, 0, wn_qkv_w, wn_qkv_b, wn_rpb, wn_pw, wn_pb, ybuf, 0);
  swin_k<<<1024, 256, 0, stream>>>(x, 64, 4, sw_qkv_w, sw_qkv_b, sw_rpb, sw_pw, sw_pb, ybuf, 32);

  conv_cln_k<128, 0><<<dim3(512, 1, 4), 256, 0, stream>>>(
      ybuf, BSTRX, fc_w, fc_b, ln_g, ln_b, x, nullptr, x2);

  conv1x1_k<128, 1, 0><<<dim3(256, 4, 4), 256, 0, stream>>>(
      x2, BSTRX, PIMG, m1_w, m1_b, hbuf, 4194304L, PIMG);
  conv_cln_k<256, 1><<<dim3(512, 1, 4), 256, 0, stream>>>(
      hbuf, 4194304L, m2_w, m2_b, n2_g, n2_b, x, x2, out);
}

// Round 3
// 431.382 us; speedup vs baseline: 2.3586x; 1.6667x over previous
//
#include <hip/hip_runtime.h>
#include <hip/hip_bf16.h>
#include <cstdint>

// ---------------------------------------------------------------------------
// GABlock, channel-last bf16-MFMA pipeline.
// Activations live as [row=pixel][channel] (channel-last); GEMMs use
// mfma_f32_16x16x32_bf16 with fp32 accumulation; LN/softmax/gelu/residual fp32.
// ---------------------------------------------------------------------------

typedef __attribute__((ext_vector_type(8))) short bf8_t;   // 8 bf16 (4 VGPR)
typedef __attribute__((ext_vector_type(4))) float f4_t;    // 4 f32 acc

__device__ __forceinline__ float bf2f(unsigned short u) {
  union { unsigned int i; float f; } x; x.i = ((unsigned int)u) << 16; return x.f;
}
__device__ __forceinline__ unsigned short f2bf(float f) {
  union { float f; unsigned int i; } x; x.f = f;
  unsigned int r = x.i + 0x7FFFu + ((x.i >> 16) & 1u);
  return (unsigned short)(r >> 16);
}
__device__ __forceinline__ unsigned int pk2(float a, float b) {
  return (unsigned int)f2bf(a) | ((unsigned int)f2bf(b) << 16);
}

#define MB (1048576L)

// ---------------- dynamic position bias MLP --------------------------------
__global__ void pos_mlp_k(const float* __restrict__ w1, const float* __restrict__ b1,
                          const float* __restrict__ w2, const float* __restrict__ b2,
                          const float* __restrict__ w3, const float* __restrict__ b3,
                          float* __restrict__ table) {
  int j = blockIdx.x * 256 + threadIdx.x;
  if (j >= 961) return;
  float chv = (float)(j / 31) - 15.0f;
  float cwv = (float)(j % 31) - 15.0f;
  float t1[16], t2[16];
#pragma unroll
  for (int i = 0; i < 16; ++i) {
    float s = fmaf(w1[i * 2], chv, fmaf(w1[i * 2 + 1], cwv, b1[i]));
    t1[i] = fmaxf(s, 0.0f);
  }
#pragma unroll
  for (int i = 0; i < 16; ++i) {
    float s = b2[i];
#pragma unroll
    for (int k = 0; k < 16; ++k) s = fmaf(w2[i * 16 + k], t1[k], s);
    t2[i] = fmaxf(s, 0.0f);
  }
#pragma unroll
  for (int hh = 0; hh < 4; ++hh) {
    float s = b3[hh];
#pragma unroll
    for (int k = 0; k < 16; ++k) s = fmaf(w3[hh * 16 + k], t2[k], s);
    table[j * 4 + hh] = s;
  }
}

__global__ void pbias_gather_k(const float* __restrict__ table, float* __restrict__ pbias) {
  int t = blockIdx.x * 256 + threadIdx.x;
  int hh = t >> 16;
  int r = t & 65535;
  int n = r >> 8;
  int m = r & 255;
  int idx = ((n >> 4) - (m >> 4) + 15) * 31 + ((n & 15) - (m & 15) + 15);
  pbias[t] = table[idx * 4 + hh];
}

// ---------------- NCHW fp32 -> channel-last fp32 (and back) ----------------
__global__ __launch_bounds__(256) void tin_k(const float* __restrict__ x,
                                             float* __restrict__ xTf) {
  __shared__ float tile[64][132];
  const int b = blockIdx.z, px0 = blockIdx.x * 64, tid = threadIdx.x;
#pragma unroll
  for (int i = 0; i < 8; ++i) {
    int e = i * 256 + tid;
    int c = e >> 4, p4 = (e & 15) * 4;
    float4 v = *(const float4*)(x + (((size_t)(b * 128 + c)) << 14) + px0 + p4);
    tile[p4][c] = v.x; tile[p4 + 1][c] = v.y; tile[p4 + 2][c] = v.z; tile[p4 + 3][c] = v.w;
  }
  __syncthreads();
#pragma unroll
  for (int i = 0; i < 8; ++i) {
    int e = i * 256 + tid;
    int px = e >> 5, c4 = (e & 31) * 4;
    float4 v = make_float4(tile[px][c4], tile[px][c4 + 1], tile[px][c4 + 2], tile[px][c4 + 3]);
    *(float4*)(xTf + ((size_t)(b * 16384 + px0 + px)) * 128 + c4) = v;
  }
}

__global__ __launch_bounds__(256) void tout_k(const float* __restrict__ outT,
                                              float* __restrict__ out) {
  __shared__ float tile[64][132];
  const int b = blockIdx.z, px0 = blockIdx.x * 64, tid = threadIdx.x;
#pragma unroll
  for (int i = 0; i < 8; ++i) {
    int e = i * 256 + tid;
    int px = e >> 5, c4 = (e & 31) * 4;
    float4 v = *(const float4*)(outT + ((size_t)(b * 16384 + px0 + px)) * 128 + c4);
    tile[px][c4] = v.x; tile[px][c4 + 1] = v.y; tile[px][c4 + 2] = v.z; tile[px][c4 + 3] = v.w;
  }
  __syncthreads();
#pragma unroll
  for (int i = 0; i < 8; ++i) {
    int e = i * 256 + tid;
    int c = e >> 4, p4 = (e & 15) * 4;
    float4 v = make_float4(tile[p4][c], tile[p4 + 1][c], tile[p4 + 2][c], tile[p4 + 3][c]);
    *(float4*)(out + (((size_t)(b * 128 + c)) << 14) + px0 + p4) = v;
  }
}

// ---------------- generic bf16-MFMA GEMM -----------------------------------
// D[px][co] = act[px][ci] * W[co][ci]^T (+bias, +epilogue)
// Block: 128 px rows x BN=NF*16 cols, 4 waves (wave = 32 px x BN).
// K in chunks of 64, both operands staged to LDS as [row][64] bf16 with
// 16B-chunk XOR swizzle (chunk ^= row&7) -> 2-way-max bank aliasing (free).
// EPI: 0 plain->bf16, 1 gelu->bf16, 2 cLN+res_f32->bf16, 3 cLN+res_bf16+res_f32->f32
// OSHUF: 0 none, 1 grid-shuffle row remap, 2 grid-unshuffle row remap
template <int NF, int KC, int AF32, int EPI, int OSHUF>
__global__ __launch_bounds__(256) void gemm_k(
    const void* __restrict__ A, int a_rs, int a_c0,
    const float* __restrict__ W, const float* __restrict__ bias,
    const float* __restrict__ g, const float* __restrict__ bb,
    const float* __restrict__ resf, const unsigned short* __restrict__ resb,
    void* __restrict__ out, int o_rs, int o_c0) {
  __shared__ __align__(16) char Asw[128 * 128];
  __shared__ __align__(16) char Bsw[NF * 16 * 128];
  const int tid = threadIdx.x;
  const int lane = tid & 63, wv = tid >> 6, wpx = wv * 32;
  const int lr = lane & 15, lg = lane >> 4;
  const int px0 = blockIdx.x * 128;
  const int co0 = blockIdx.y * (NF * 16);

  f4_t acc[2][NF];
#pragma unroll
  for (int mf = 0; mf < 2; ++mf)
#pragma unroll
    for (int nf = 0; nf < NF; ++nf) acc[mf][nf] = (f4_t){0.f, 0.f, 0.f, 0.f};

  for (int kc = 0; kc < KC; ++kc) {
    const int k0 = kc * 64;
    if (kc) __syncthreads();
    // stage A (activations)
#pragma unroll
    for (int i = 0; i < 4; ++i) {
      int e = i * 256 + tid;
      int row = e >> 3, q8 = e & 7;
      char* dst = Asw + row * 128 + ((q8 ^ (row & 7)) << 4);
      if (AF32) {
        const float* src = (const float*)A + (size_t)(px0 + row) * a_rs + a_c0 + k0 + q8 * 8;
        float4 v0 = *(const float4*)src, v1 = *(const float4*)(src + 4);
        uint4 pk;
        pk.x = pk2(v0.x, v0.y); pk.y = pk2(v0.z, v0.w);
        pk.z = pk2(v1.x, v1.y); pk.w = pk2(v1.z, v1.w);
        *(uint4*)dst = pk;
      } else {
        const unsigned short* src =
            (const unsigned short*)A + (size_t)(px0 + row) * a_rs + a_c0 + k0 + q8 * 8;
        *(uint4*)dst = *(const uint4*)src;
      }
    }
    // stage W (fp32 -> bf16)
#pragma unroll
    for (int i = 0; i < NF / 2; ++i) {
      int e = i * 256 + tid;
      int row = e >> 3, q8 = e & 7;
      const float* src = W + (size_t)(co0 + row) * (KC * 64) + k0 + q8 * 8;
      float4 v0 = *(const float4*)src, v1 = *(const float4*)(src + 4);
      uint4 pk;
      pk.x = pk2(v0.x, v0.y); pk.y = pk2(v0.z, v0.w);
      pk.z = pk2(v1.x, v1.y); pk.w = pk2(v1.z, v1.w);
      *(uint4*)(Bsw + row * 128 + ((q8 ^ (row & 7)) << 4)) = pk;
    }
    __syncthreads();
#pragma unroll
    for (int ks = 0; ks < 2; ++ks) {
      const int xk = (((ks * 4) + lg) ^ (lane & 7)) << 4;
      bf8_t av[2], bv[NF];
#pragma unroll
      for (int mf = 0; mf < 2; ++mf)
        av[mf] = *(const bf8_t*)(Asw + (wpx + mf * 16 + lr) * 128 + xk);
#pragma unroll
      for (int nf = 0; nf < NF; ++nf)
        bv[nf] = *(const bf8_t*)(Bsw + (nf * 16 + lr) * 128 + xk);
#pragma unroll
      for (int mf = 0; mf < 2; ++mf)
#pragma unroll
        for (int nf = 0; nf < NF; ++nf)
          acc[mf][nf] = __builtin_amdgcn_mfma_f32_16x16x32_bf16(av[mf], bv[nf], acc[mf][nf], 0, 0, 0);
    }
  }

  float bco[NF];
#pragma unroll
  for (int nf = 0; nf < NF; ++nf) bco[nf] = bias[co0 + nf * 16 + lr];

  if constexpr (EPI >= 2) {
    // bias first, then channel-LN over 128 co (= 8 nf * 16 lanes), fp32
    float gv[NF], bbv[NF];
#pragma unroll
    for (int nf = 0; nf < NF; ++nf) { gv[nf] = g[nf * 16 + lr]; bbv[nf] = bb[nf * 16 + lr]; }
#pragma unroll
    for (int mf = 0; mf < 2; ++mf)
#pragma unroll
      for (int nf = 0; nf < NF; ++nf)
#pragma unroll
        for (int r = 0; r < 4; ++r) acc[mf][nf][r] += bco[nf];
#pragma unroll
    for (int mf = 0; mf < 2; ++mf) {
#pragma unroll
      for (int r = 0; r < 4; ++r) {
        float s = 0.f, q = 0.f;
#pragma unroll
        for (int nf = 0; nf < NF; ++nf) {
          float v = acc[mf][nf][r];
          s += v; q += v * v;
        }
#pragma unroll
        for (int msk = 1; msk < 16; msk <<= 1) {
          s += __shfl_xor(s, msk);
          q += __shfl_xor(q, msk);
        }
        float mu = s * (1.0f / 128.0f);
        float var = q * (1.0f / 128.0f) - mu * mu;
        float rstd = rsqrtf(var + 1e-5f);
        int px_e = px0 + wpx + mf * 16 + lg * 4 + r;
        const float* xr = resf + (size_t)px_e * 128 + lr;
        if constexpr (EPI == 2) {
          unsigned short* op = (unsigned short*)out + (size_t)px_e * o_rs + lr;
#pragma unroll
          for (int nf = 0; nf < NF; ++nf) {
            float v = (acc[mf][nf][r] - mu) * rstd * gv[nf] + bbv[nf] + xr[nf * 16];
            op[nf * 16] = f2bf(v);
          }
        } else {
          const unsigned short* x2r = resb + (size_t)px_e * 128 + lr;
          float* op = (float*)out + (size_t)px_e * 128 + lr;
#pragma unroll
          for (int nf = 0; nf < NF; ++nf) {
            float v = (acc[mf][nf][r] - mu) * rstd * gv[nf] + bbv[nf] + xr[nf * 16] + bf2f(x2r[nf * 16]);
            op[nf * 16] = v;
          }
        }
      }
    }
  } else {
#pragma unroll
    for (int mf = 0; mf < 2; ++mf) {
#pragma unroll
      for (int r = 0; r < 4; ++r) {
        int px_e = px0 + wpx + mf * 16 + lg * 4 + r;
        size_t orow;
        if constexpr (OSHUF == 0) {
          orow = (size_t)px_e;
        } else if constexpr (OSHUF == 1) {
          int b = px_e >> 14, p = px_e & 16383, hh = p >> 7, w_ = p & 127;
          orow = (size_t)(b * 64 + (hh & 7) * 8 + (w_ & 7)) * 256 + ((hh >> 3) * 16 + (w_ >> 3));
        } else {
          int gbb = px_e >> 8, n = px_e & 255;
          int b = gbb >> 6, ih = (gbb >> 3) & 7, iw = gbb & 7;
          orow = (size_t)b * 16384 + ((n >> 4) * 8 + ih) * 128 + (n & 15) * 8 + iw;
        }
        unsigned short* op = (unsigned short*)out + orow * o_rs + o_c0 + co0 + lr;
#pragma unroll
        for (int nf = 0; nf < NF; ++nf) {
          float v = acc[mf][nf][r] + bco[nf];
          if constexpr (EPI == 1) v = 0.5f * v * (1.0f + erff(v * 0.7071067811865475f));
          op[nf * 16] = f2bf(v);
        }
      }
    }
  }
}

// ---------------- grid attention (channel-last, N=256, hd=16) --------------
__global__ __launch_bounds__(256) void gattn_k(
    const unsigned short* __restrict__ Q, int q_rs, int q_c0,
    const unsigned short* __restrict__ K, int k_rs, int k_c0,
    const unsigned short* __restrict__ V, int v_rs, int v_c0,
    const float* __restrict__ pbias, unsigned short* __restrict__ outb, int o_rs, int o_c0) {
  __shared__ float Ks[256][20];
  __shared__ float Vs[256][20];
  const int gb = blockIdx.x, h = blockIdx.y, tid = threadIdx.x;
  {
    const unsigned short* kp = K + (size_t)(gb * 256 + tid) * k_rs + k_c0 + h * 16;
    const unsigned short* vp = V + (size_t)(gb * 256 + tid) * v_rs + v_c0 + h * 16;
    uint4 ka = *(const uint4*)kp, kb = *(const uint4*)(kp + 8);
    uint4 va = *(const uint4*)vp, vb = *(const uint4*)(vp + 8);
    unsigned int kw[8] = {ka.x, ka.y, ka.z, ka.w, kb.x, kb.y, kb.z, kb.w};
    unsigned int vw[8] = {va.x, va.y, va.z, va.w, vb.x, vb.y, vb.z, vb.w};
#pragma unroll
    for (int j = 0; j < 8; ++j) {
      Ks[tid][2 * j] = bf2f((unsigned short)(kw[j] & 0xffff));
      Ks[tid][2 * j + 1] = bf2f((unsigned short)(kw[j] >> 16));
      Vs[tid][2 * j] = bf2f((unsigned short)(vw[j] & 0xffff));
      Vs[tid][2 * j + 1] = bf2f((unsigned short)(vw[j] >> 16));
    }
  }
  float q[16];
  {
    const unsigned short* qp = Q + (size_t)(gb * 256 + tid) * q_rs + q_c0 + h * 16;
    uint4 qa = *(const uint4*)qp, qb = *(const uint4*)(qp + 8);
    unsigned int qw[8] = {qa.x, qa.y, qa.z, qa.w, qb.x, qb.y, qb.z, qb.w};
#pragma unroll
    for (int j = 0; j < 8; ++j) {
      q[2 * j] = bf2f((unsigned short)(qw[j] & 0xffff)) * 0.25f;
      q[2 * j + 1] = bf2f((unsigned short)(qw[j] >> 16)) * 0.25f;
    }
  }
  __syncthreads();

  const float* bp = pbias + ((size_t)(h << 8) + tid) * 256;
  float mrun = -1e30f, lrun = 0.0f;
  float acc[16];
#pragma unroll
  for (int d = 0; d < 16; ++d) acc[d] = 0.0f;

  for (int m0 = 0; m0 < 256; m0 += 32) {
    float s[32];
#pragma unroll
    for (int i = 0; i < 8; ++i) {
      float4 bv = *(const float4*)&bp[m0 + 4 * i];
      s[4 * i] = bv.x; s[4 * i + 1] = bv.y; s[4 * i + 2] = bv.z; s[4 * i + 3] = bv.w;
    }
#pragma unroll
    for (int i = 0; i < 32; ++i) {
      const float4* kr = (const float4*)&Ks[m0 + i][0];
      float4 k0 = kr[0], k1 = kr[1], k2 = kr[2], k3 = kr[3];
      float v = s[i];
      v = fmaf(q[0], k0.x, v); v = fmaf(q[1], k0.y, v); v = fmaf(q[2], k0.z, v); v = fmaf(q[3], k0.w, v);
      v = fmaf(q[4], k1.x, v); v = fmaf(q[5], k1.y, v); v = fmaf(q[6], k1.z, v); v = fmaf(q[7], k1.w, v);
      v = fmaf(q[8], k2.x, v); v = fmaf(q[9], k2.y, v); v = fmaf(q[10], k2.z, v); v = fmaf(q[11], k2.w, v);
      v = fmaf(q[12], k3.x, v); v = fmaf(q[13], k3.y, v); v = fmaf(q[14], k3.z, v); v = fmaf(q[15], k3.w, v);
      s[i] = v;
    }
    float mx = s[0];
#pragma unroll
    for (int i = 1; i < 32; ++i) mx = fmaxf(mx, s[i]);
    if (mx > mrun) {
      float cc = __expf(mrun - mx);
      lrun *= cc;
#pragma unroll
      for (int d = 0; d < 16; ++d) acc[d] *= cc;
      mrun = mx;
    }
    float ls = 0.0f;
#pragma unroll
    for (int i = 0; i < 32; ++i) {
      s[i] = __expf(s[i] - mrun);
      ls += s[i];
    }
    lrun += ls;
#pragma unroll
    for (int i = 0; i < 32; ++i) {
      const float4* vr = (const float4*)&Vs[m0 + i][0];
      float4 v0 = vr[0], v1 = vr[1], v2 = vr[2], v3 = vr[3];
      float p = s[i];
      acc[0] = fmaf(p, v0.x, acc[0]); acc[1] = fmaf(p, v0.y, acc[1]);
      acc[2] = fmaf(p, v0.z, acc[2]); acc[3] = fmaf(p, v0.w, acc[3]);
      acc[4] = fmaf(p, v1.x, acc[4]); acc[5] = fmaf(p, v1.y, acc[5]);
      acc[6] = fmaf(p, v1.z, acc[6]); acc[7] = fmaf(p, v1.w, acc[7]);
      acc[8] = fmaf(p, v2.x, acc[8]); acc[9] = fmaf(p, v2.y, acc[9]);
      acc[10] = fmaf(p, v2.z, acc[10]); acc[11] = fmaf(p, v2.w, acc[11]);
      acc[12] = fmaf(p, v3.x, acc[12]); acc[13] = fmaf(p, v3.y, acc[13]);
      acc[14] = fmaf(p, v3.z, acc[14]); acc[15] = fmaf(p, v3.w, acc[15]);
    }
  }
  float inv = 1.0f / lrun;
  uint4 o0, o1;
  o0.x = pk2(acc[0] * inv, acc[1] * inv);  o0.y = pk2(acc[2] * inv, acc[3] * inv);
  o0.z = pk2(acc[4] * inv, acc[5] * inv);  o0.w = pk2(acc[6] * inv, acc[7] * inv);
  o1.x = pk2(acc[8] * inv, acc[9] * inv);  o1.y = pk2(acc[10] * inv, acc[11] * inv);
  o1.z = pk2(acc[12] * inv, acc[13] * inv); o1.w = pk2(acc[14] * inv, acc[15] * inv);
  unsigned short* op = outb + (size_t)(gb * 256 + tid) * o_rs + o_c0 + h * 16;
  *(uint4*)op = o0;
  *(uint4*)(op + 8) = o1;
}

// ---------------- fused swin window attention (channel-last I/O) -----------
__global__ __launch_bounds__(256) void swin_k(
    const float* __restrict__ xTf, int c0, int shift,
    const float* __restrict__ qkvw, const float* __restrict__ qkvb,
    const float* __restrict__ rpb, const float* __restrict__ pw,
    const float* __restrict__ pb, unsigned short* __restrict__ yT, int yc0) {
  __shared__ float xt[64][33];
  __shared__ float qkvs[96][64];
  __shared__ float rps[900];
  __shared__ float ao[64][33];
  const int wb = blockIdx.x;
  const int b = wb >> 8;
  const int wrem = wb & 255;
  const int wh = wrem >> 4, ww = wrem & 15;
  const int tid = threadIdx.x;

  for (int i = tid; i < 900; i += 256) rps[i] = rpb[i];
  {
    int n = tid & 63, cg = tid >> 6;
    int r = n >> 3, c_ = n & 7;
    int hsrc = (wh * 8 + r + shift) & 127;
    int wsrc = (ww * 8 + c_ + shift) & 127;
    const float* xr = xTf + ((size_t)(b * 16384 + hsrc * 128 + wsrc)) * 128 + c0 + cg * 8;
    float4 v0 = *(const float4*)xr, v1 = *(const float4*)(xr + 4);
    xt[n][cg * 8 + 0] = v0.x; xt[n][cg * 8 + 1] = v0.y;
    xt[n][cg * 8 + 2] = v0.z; xt[n][cg * 8 + 3] = v0.w;
    xt[n][cg * 8 + 4] = v1.x; xt[n][cg * 8 + 5] = v1.y;
    xt[n][cg * 8 + 6] = v1.z; xt[n][cg * 8 + 7] = v1.w;
  }
  __syncthreads();
  {
    int n = tid & 63, cg = tid >> 6;
    for (int co = cg; co < 96; co += 4) {
      float s = qkvb[co];
      const float* wr = qkvw + co * 32;
#pragma unroll
      for (int ci = 0; ci < 32; ++ci) s = fmaf(wr[ci], xt[n][ci], s);
      qkvs[co][n] = s;
    }
  }
  __syncthreads();
  {
    const int h = tid >> 6, n = tid & 63;
    float q[8];
#pragma unroll
    for (int d = 0; d < 8; ++d) q[d] = qkvs[h * 8 + d][n] * 0.35355339059327373f;
    const int rn = n >> 3, cn = n & 7;
    int regn = 0;
    if (shift > 0) {
      int hr = wh * 8 + rn, wr_ = ww * 8 + cn;
      int rh = hr < 120 ? 0 : (hr < 124 ? 1 : 2);
      int rw = wr_ < 120 ? 0 : (wr_ < 124 ? 1 : 2);
      regn = rh * 3 + rw;
    }
    float s[64];
#pragma unroll
    for (int m = 0; m < 64; ++m) {
      float v = 0.0f;
#pragma unroll
      for (int d = 0; d < 8; ++d) v = fmaf(q[d], qkvs[32 + h * 8 + d][m], v);
      int rm = m >> 3, cm = m & 7;
      v += rps[((rn - rm + 7) * 15 + (cn - cm + 7)) * 4 + h];
      if (shift > 0) {
        int hr = wh * 8 + rm, wr_ = ww * 8 + cm;
        int rh = hr < 120 ? 0 : (hr < 124 ? 1 : 2);
        int rw = wr_ < 120 ? 0 : (wr_ < 124 ? 1 : 2);
        if (rh * 3 + rw != regn) v -= 100.0f;
      }
      s[m] = v;
    }
    float mx = -1e30f;
#pragma unroll
    for (int m = 0; m < 64; ++m) mx = fmaxf(mx, s[m]);
    float l = 0.0f;
#pragma unroll
    for (int m = 0; m < 64; ++m) {
      float p = __expf(s[m] - mx);
      s[m] = p;
      l += p;
    }
    float inv = 1.0f / l;
    float o[8];
#pragma unroll
    for (int d = 0; d < 8; ++d) o[d] = 0.0f;
#pragma unroll
    for (int m = 0; m < 64; ++m) {
      float p = s[m];
#pragma unroll
      for (int d = 0; d < 8; ++d) o[d] = fmaf(p, qkvs[64 + h * 8 + d][m], o[d]);
    }
#pragma unroll
    for (int d = 0; d < 8; ++d) ao[n][h * 8 + d] = o[d] * inv;
  }
  __syncthreads();
  {
    int n = tid & 63, cg = tid >> 6;
    int r = n >> 3, c_ = n & 7;
    int hdst = (wh * 8 + r + shift) & 127;
    int wdst = (ww * 8 + c_ + shift) & 127;
    float o8[8];
#pragma unroll
    for (int k = 0; k < 8; ++k) {
      int co = cg * 8 + k;
      float s = pb[co];
      const float* wr = pw + co * 32;
#pragma unroll
      for (int ci = 0; ci < 32; ++ci) s = fmaf(wr[ci], ao[n][ci], s);
      o8[k] = s;
    }
    uint4 pk;
    pk.x = pk2(o8[0], o8[1]); pk.y = pk2(o8[2], o8[3]);
    pk.z = pk2(o8[4], o8[5]); pk.w = pk2(o8[6], o8[7]);
    *(uint4*)(yT + ((size_t)(b * 16384 + hdst * 128 + wdst)) * 128 + yc0 + cg * 8) = pk;
  }
}

// ---------------------------------------------------------------------------
extern "C" void kernel_launch(void* const* d_in, const int* in_sizes, int n_in,
                              void* d_out, int out_size, void* d_ws, size_t ws_size,
                              hipStream_t stream) {
  (void)in_sizes; (void)n_in; (void)out_size; (void)ws_size;
  const float* x        = (const float*)d_in[0];
  const float* ln_g     = (const float*)d_in[1];
  const float* ln_b     = (const float*)d_in[2];
  const float* ga_qkv_w = (const float*)d_in[3];
  const float* ga_qkv_b = (const float*)d_in[4];
  const float* ga_gp_w  = (const float*)d_in[5];
  const float* ga_gp_b  = (const float*)d_in[6];
  const float* pos_w1   = (const float*)d_in[7];
  const float* pos_b1   = (const float*)d_in[8];
  const float* pos_w2   = (const float*)d_in[9];
  const float* pos_b2   = (const float*)d_in[10];
  const float* pos_w3   = (const float*)d_in[11];
  const float* pos_b3   = (const float*)d_in[12];
  const float* a1_pw    = (const float*)d_in[13];
  const float* a1_pb    = (const float*)d_in[14];
  const float* a2_pw    = (const float*)d_in[15];
  const float* a2_pb    = (const float*)d_in[16];
  const float* sw_qkv_w = (const float*)d_in[17];
  const float* sw_qkv_b = (const float*)d_in[18];
  const float* sw_rpb   = (const float*)d_in[19];
  const float* sw_pw    = (const float*)d_in[20];
  const float* sw_pb    = (const float*)d_in[21];
  const float* wn_qkv_w = (const float*)d_in[22];
  const float* wn_qkv_b = (const float*)d_in[23];
  const float* wn_rpb   = (const float*)d_in[24];
  const float* wn_pw    = (const float*)d_in[25];
  const float* wn_pb    = (const float*)d_in[26];
  const float* fc_w     = (const float*)d_in[27];
  const float* fc_b     = (const float*)d_in[28];
  const float* n2_g     = (const float*)d_in[29];
  const float* n2_b     = (const float*)d_in[30];
  const float* m1_w     = (const float*)d_in[31];
  const float* m1_b     = (const float*)d_in[32];
  const float* m2_w     = (const float*)d_in[33];
  const float* m2_b     = (const float*)d_in[34];
  float* out = (float*)d_out;
  char* base = (char*)d_ws;

  // workspace (lifetime-aliased): peak ~114 MB
  float*          xTf    = (float*)(base);                    // 32 MB, alive thru M2
  unsigned short* qkvT   = (unsigned short*)(base + 32 * MB); // 24 MB, dead after A2
  unsigned short* xgridT = (unsigned short*)(base + 56 * MB); //  8 MB, dead after A2
  unsigned short* t1T    = (unsigned short*)(base + 64 * MB); //  8 MB
  unsigned short* t1pT   = (unsigned short*)(base + 72 * MB); //  8 MB
  unsigned short* yT     = (unsigned short*)(base + 80 * MB); // 16 MB, dead after FC
  unsigned short* x2T    = (unsigned short*)(base + 96 * MB); // 16 MB, alive thru M2
  unsigned short* hT     = (unsigned short*)(base + 32 * MB); // 32 MB alias (qkvT+xgridT)
  float*          outT   = (float*)(base + 64 * MB);          // 32 MB alias (t1T+t1pT+yT)
  float*          pbias  = (float*)(base + 112 * MB);         //  1 MB
  float*          ptab   = (float*)(base + 113 * MB);

  pos_mlp_k<<<4, 256, 0, stream>>>(pos_w1, pos_b1, pos_w2, pos_b2, pos_w3, pos_b3, ptab);
  pbias_gather_k<<<1024, 256, 0, stream>>>(ptab, pbias);

  // NCHW -> channel-last fp32
  tin_k<<<dim3(256, 1, 4), 256, 0, stream>>>(x, xTf);

  // grid branch: qkv (64->192) and gp (64->64), grid-shuffled channel-last out
  gemm_k<4, 1, 1, 0, 1><<<dim3(512, 3, 1), 256, 0, stream>>>(
      xTf, 128, 0, ga_qkv_w, ga_qkv_b, nullptr, nullptr, nullptr, nullptr, qkvT, 192, 0);
  gemm_k<4, 1, 1, 0, 1><<<dim3(512, 1, 1), 256, 0, stream>>>(
      xTf, 128, 0, ga_gp_w, ga_gp_b, nullptr, nullptr, nullptr, nullptr, xgridT, 64, 0);

  // attn1: Q=xgrid, K=qkv.k, V=qkv.v -> t1 ; proj a1 -> t1p
  gattn_k<<<dim3(256, 4), 256, 0, stream>>>(
      xgridT, 64, 0, qkvT, 192, 64, qkvT, 192, 128, pbias, t1T, 64, 0);
  gemm_k<4, 1, 0, 0, 0><<<dim3(512, 1, 1), 256, 0, stream>>>(
      t1T, 64, 0, a1_pw, a1_pb, nullptr, nullptr, nullptr, nullptr, t1pT, 64, 0);

  // attn2: Q=qkv.q, K=xgrid, V=t1p -> t2(=t1 buf) ; proj a2 + unshuffle -> yT[64:128]
  gattn_k<<<dim3(256, 4), 256, 0, stream>>>(
      qkvT, 192, 0, xgridT, 64, 0, t1pT, 64, 0, pbias, t1T, 64, 0);
  gemm_k<4, 1, 0, 0, 2><<<dim3(512, 1, 1), 256, 0, stream>>>(
      t1T, 64, 0, a2_pw, a2_pb, nullptr, nullptr, nullptr, nullptr, yT, 128, 64);

  // window branches -> yT[0:32] (plain, from x[96:128]) and yT[32:64] (shifted, x[64:96])
  swin_k<<<1024, 256, 0, stream>>>(xTf, 96, 0, wn_qkv_w, wn_qkv_b, wn_rpb, wn_pw, wn_pb, yT, 0);
  swin_k<<<1024, 256, 0, stream>>>(xTf, 64, 4, sw_qkv_w, sw_qkv_b, sw_rpb, sw_pw, sw_pb, yT, 32);

  // fc + cLN + residual(x) -> x2T (bf16 channel-last)
  gemm_k<8, 2, 0, 2, 0><<<dim3(512, 1, 1), 256, 0, stream>>>(
      yT, 128, 0, fc_w, fc_b, ln_g, ln_b, xTf, nullptr, x2T, 128, 0);

  // MLP: m1 (gelu) -> hT ; m2 + cLN + x2 + shortcut -> outT (f32 channel-last)
  gemm_k<8, 2, 0, 1, 0><<<dim3(512, 2, 1), 256, 0, stream>>>(
      x2T, 128, 0, m1_w, m1_b, nullptr, nullptr, nullptr, nullptr, hT, 256, 0);
  gemm_k<8, 4, 0, 3, 0><<<dim3(512, 1, 1), 256, 0, stream>>>(
      hT, 256, 0, m2_w, m2_b, n2_g, n2_b, xTf, x2T, outT, 128, 0);

  // channel-last -> NCHW
  tout_k<<<dim3(256, 1, 4), 256, 0, stream>>>(outT, out);
}

// Round 4
// 307.536 us; speedup vs baseline: 3.3085x; 1.4027x over previous
//
#include <hip/hip_runtime.h>
#include <hip/hip_bf16.h>
#include <cstdint>

// ---------------------------------------------------------------------------
// GABlock, channel-last bf16-MFMA pipeline.
// R4: grid attention rewritten as MFMA flash attention (swapped QK^T,
//     zero-padded K-dim, P repacked through wave-private LDS for PV).
// ---------------------------------------------------------------------------

typedef __attribute__((ext_vector_type(8))) short bf8_t;   // 8 bf16 (4 VGPR)
typedef __attribute__((ext_vector_type(4))) float f4_t;    // 4 f32 acc

__device__ __forceinline__ float bf2f(unsigned short u) {
  union { unsigned int i; float f; } x; x.i = ((unsigned int)u) << 16; return x.f;
}
__device__ __forceinline__ unsigned short f2bf(float f) {
  union { float f; unsigned int i; } x; x.f = f;
  unsigned int r = x.i + 0x7FFFu + ((x.i >> 16) & 1u);
  return (unsigned short)(r >> 16);
}
__device__ __forceinline__ unsigned int pk2(float a, float b) {
  return (unsigned int)f2bf(a) | ((unsigned int)f2bf(b) << 16);
}

#define MB (1048576L)

// ---------------- dynamic position bias MLP --------------------------------
__global__ void pos_mlp_k(const float* __restrict__ w1, const float* __restrict__ b1,
                          const float* __restrict__ w2, const float* __restrict__ b2,
                          const float* __restrict__ w3, const float* __restrict__ b3,
                          float* __restrict__ table) {
  int j = blockIdx.x * 256 + threadIdx.x;
  if (j >= 961) return;
  float chv = (float)(j / 31) - 15.0f;
  float cwv = (float)(j % 31) - 15.0f;
  float t1[16], t2[16];
#pragma unroll
  for (int i = 0; i < 16; ++i) {
    float s = fmaf(w1[i * 2], chv, fmaf(w1[i * 2 + 1], cwv, b1[i]));
    t1[i] = fmaxf(s, 0.0f);
  }
#pragma unroll
  for (int i = 0; i < 16; ++i) {
    float s = b2[i];
#pragma unroll
    for (int k = 0; k < 16; ++k) s = fmaf(w2[i * 16 + k], t1[k], s);
    t2[i] = fmaxf(s, 0.0f);
  }
#pragma unroll
  for (int hh = 0; hh < 4; ++hh) {
    float s = b3[hh];
#pragma unroll
    for (int k = 0; k < 16; ++k) s = fmaf(w3[hh * 16 + k], t2[k], s);
    table[j * 4 + hh] = s;
  }
}

// pbT[h][m][q] = bias for query q, key m (transposed for the swapped-QK MFMA)
__global__ void pbT_gather_k(const float* __restrict__ table, float* __restrict__ pbT) {
  int t = blockIdx.x * 256 + threadIdx.x;   // 4*256*256
  int hh = t >> 16;
  int r = t & 65535;
  int m = r >> 8;
  int q = r & 255;
  int idx = ((q >> 4) - (m >> 4) + 15) * 31 + ((q & 15) - (m & 15) + 15);
  pbT[t] = table[idx * 4 + hh];
}

// ---------------- NCHW fp32 -> channel-last fp32 (and back) ----------------
__global__ __launch_bounds__(256) void tin_k(const float* __restrict__ x,
                                             float* __restrict__ xTf) {
  __shared__ float tile[64][132];
  const int b = blockIdx.z, px0 = blockIdx.x * 64, tid = threadIdx.x;
#pragma unroll
  for (int i = 0; i < 8; ++i) {
    int e = i * 256 + tid;
    int c = e >> 4, p4 = (e & 15) * 4;
    float4 v = *(const float4*)(x + (((size_t)(b * 128 + c)) << 14) + px0 + p4);
    tile[p4][c] = v.x; tile[p4 + 1][c] = v.y; tile[p4 + 2][c] = v.z; tile[p4 + 3][c] = v.w;
  }
  __syncthreads();
#pragma unroll
  for (int i = 0; i < 8; ++i) {
    int e = i * 256 + tid;
    int px = e >> 5, c4 = (e & 31) * 4;
    float4 v = make_float4(tile[px][c4], tile[px][c4 + 1], tile[px][c4 + 2], tile[px][c4 + 3]);
    *(float4*)(xTf + ((size_t)(b * 16384 + px0 + px)) * 128 + c4) = v;
  }
}

__global__ __launch_bounds__(256) void tout_k(const float* __restrict__ outT,
                                              float* __restrict__ out) {
  __shared__ float tile[64][132];
  const int b = blockIdx.z, px0 = blockIdx.x * 64, tid = threadIdx.x;
#pragma unroll
  for (int i = 0; i < 8; ++i) {
    int e = i * 256 + tid;
    int px = e >> 5, c4 = (e & 31) * 4;
    float4 v = *(const float4*)(outT + ((size_t)(b * 16384 + px0 + px)) * 128 + c4);
    tile[px][c4] = v.x; tile[px][c4 + 1] = v.y; tile[px][c4 + 2] = v.z; tile[px][c4 + 3] = v.w;
  }
  __syncthreads();
#pragma unroll
  for (int i = 0; i < 8; ++i) {
    int e = i * 256 + tid;
    int c = e >> 4, p4 = (e & 15) * 4;
    float4 v = make_float4(tile[p4][c], tile[p4 + 1][c], tile[p4 + 2][c], tile[p4 + 3][c]);
    *(float4*)(out + (((size_t)(b * 128 + c)) << 14) + px0 + p4) = v;
  }
}

// ---------------- generic bf16-MFMA GEMM -----------------------------------
template <int NF, int KC, int AF32, int EPI, int OSHUF>
__global__ __launch_bounds__(256) void gemm_k(
    const void* __restrict__ A, int a_rs, int a_c0,
    const float* __restrict__ W, const float* __restrict__ bias,
    const float* __restrict__ g, const float* __restrict__ bb,
    const float* __restrict__ resf, const unsigned short* __restrict__ resb,
    void* __restrict__ out, int o_rs, int o_c0) {
  __shared__ __align__(16) char Asw[128 * 128];
  __shared__ __align__(16) char Bsw[NF * 16 * 128];
  const int tid = threadIdx.x;
  const int lane = tid & 63, wv = tid >> 6, wpx = wv * 32;
  const int lr = lane & 15, lg = lane >> 4;
  const int px0 = blockIdx.x * 128;
  const int co0 = blockIdx.y * (NF * 16);

  f4_t acc[2][NF];
#pragma unroll
  for (int mf = 0; mf < 2; ++mf)
#pragma unroll
    for (int nf = 0; nf < NF; ++nf) acc[mf][nf] = (f4_t){0.f, 0.f, 0.f, 0.f};

  for (int kc = 0; kc < KC; ++kc) {
    const int k0 = kc * 64;
    if (kc) __syncthreads();
#pragma unroll
    for (int i = 0; i < 4; ++i) {
      int e = i * 256 + tid;
      int row = e >> 3, q8 = e & 7;
      char* dst = Asw + row * 128 + ((q8 ^ (row & 7)) << 4);
      if (AF32) {
        const float* src = (const float*)A + (size_t)(px0 + row) * a_rs + a_c0 + k0 + q8 * 8;
        float4 v0 = *(const float4*)src, v1 = *(const float4*)(src + 4);
        uint4 pk;
        pk.x = pk2(v0.x, v0.y); pk.y = pk2(v0.z, v0.w);
        pk.z = pk2(v1.x, v1.y); pk.w = pk2(v1.z, v1.w);
        *(uint4*)dst = pk;
      } else {
        const unsigned short* src =
            (const unsigned short*)A + (size_t)(px0 + row) * a_rs + a_c0 + k0 + q8 * 8;
        *(uint4*)dst = *(const uint4*)src;
      }
    }
#pragma unroll
    for (int i = 0; i < NF / 2; ++i) {
      int e = i * 256 + tid;
      int row = e >> 3, q8 = e & 7;
      const float* src = W + (size_t)(co0 + row) * (KC * 64) + k0 + q8 * 8;
      float4 v0 = *(const float4*)src, v1 = *(const float4*)(src + 4);
      uint4 pk;
      pk.x = pk2(v0.x, v0.y); pk.y = pk2(v0.z, v0.w);
      pk.z = pk2(v1.x, v1.y); pk.w = pk2(v1.z, v1.w);
      *(uint4*)(Bsw + row * 128 + ((q8 ^ (row & 7)) << 4)) = pk;
    }
    __syncthreads();
#pragma unroll
    for (int ks = 0; ks < 2; ++ks) {
      const int xk = (((ks * 4) + lg) ^ (lane & 7)) << 4;
      bf8_t av[2], bv[NF];
#pragma unroll
      for (int mf = 0; mf < 2; ++mf)
        av[mf] = *(const bf8_t*)(Asw + (wpx + mf * 16 + lr) * 128 + xk);
#pragma unroll
      for (int nf = 0; nf < NF; ++nf)
        bv[nf] = *(const bf8_t*)(Bsw + (nf * 16 + lr) * 128 + xk);
#pragma unroll
      for (int mf = 0; mf < 2; ++mf)
#pragma unroll
        for (int nf = 0; nf < NF; ++nf)
          acc[mf][nf] = __builtin_amdgcn_mfma_f32_16x16x32_bf16(av[mf], bv[nf], acc[mf][nf], 0, 0, 0);
    }
  }

  float bco[NF];
#pragma unroll
  for (int nf = 0; nf < NF; ++nf) bco[nf] = bias[co0 + nf * 16 + lr];

  if constexpr (EPI >= 2) {
    float gv[NF], bbv[NF];
#pragma unroll
    for (int nf = 0; nf < NF; ++nf) { gv[nf] = g[nf * 16 + lr]; bbv[nf] = bb[nf * 16 + lr]; }
#pragma unroll
    for (int mf = 0; mf < 2; ++mf)
#pragma unroll
      for (int nf = 0; nf < NF; ++nf)
#pragma unroll
        for (int r = 0; r < 4; ++r) acc[mf][nf][r] += bco[nf];
#pragma unroll
    for (int mf = 0; mf < 2; ++mf) {
#pragma unroll
      for (int r = 0; r < 4; ++r) {
        float s = 0.f, q = 0.f;
#pragma unroll
        for (int nf = 0; nf < NF; ++nf) {
          float v = acc[mf][nf][r];
          s += v; q += v * v;
        }
#pragma unroll
        for (int msk = 1; msk < 16; msk <<= 1) {
          s += __shfl_xor(s, msk);
          q += __shfl_xor(q, msk);
        }
        float mu = s * (1.0f / 128.0f);
        float var = q * (1.0f / 128.0f) - mu * mu;
        float rstd = rsqrtf(var + 1e-5f);
        int px_e = px0 + wpx + mf * 16 + lg * 4 + r;
        const float* xr = resf + (size_t)px_e * 128 + lr;
        if constexpr (EPI == 2) {
          unsigned short* op = (unsigned short*)out + (size_t)px_e * o_rs + lr;
#pragma unroll
          for (int nf = 0; nf < NF; ++nf) {
            float v = (acc[mf][nf][r] - mu) * rstd * gv[nf] + bbv[nf] + xr[nf * 16];
            op[nf * 16] = f2bf(v);
          }
        } else {
          const unsigned short* x2r = resb + (size_t)px_e * 128 + lr;
          float* op = (float*)out + (size_t)px_e * 128 + lr;
#pragma unroll
          for (int nf = 0; nf < NF; ++nf) {
            float v = (acc[mf][nf][r] - mu) * rstd * gv[nf] + bbv[nf] + xr[nf * 16] + bf2f(x2r[nf * 16]);
            op[nf * 16] = v;
          }
        }
      }
    }
  } else {
#pragma unroll
    for (int mf = 0; mf < 2; ++mf) {
#pragma unroll
      for (int r = 0; r < 4; ++r) {
        int px_e = px0 + wpx + mf * 16 + lg * 4 + r;
        size_t orow;
        if constexpr (OSHUF == 0) {
          orow = (size_t)px_e;
        } else if constexpr (OSHUF == 1) {
          int b = px_e >> 14, p = px_e & 16383, hh = p >> 7, w_ = p & 127;
          orow = (size_t)(b * 64 + (hh & 7) * 8 + (w_ & 7)) * 256 + ((hh >> 3) * 16 + (w_ >> 3));
        } else {
          int gbb = px_e >> 8, n = px_e & 255;
          int b = gbb >> 6, ih = (gbb >> 3) & 7, iw = gbb & 7;
          orow = (size_t)b * 16384 + ((n >> 4) * 8 + ih) * 128 + (n & 15) * 8 + iw;
        }
        unsigned short* op = (unsigned short*)out + orow * o_rs + o_c0 + co0 + lr;
#pragma unroll
        for (int nf = 0; nf < NF; ++nf) {
          float v = acc[mf][nf][r] + bco[nf];
          if constexpr (EPI == 1) v = 0.5f * v * (1.0f + erff(v * 0.7071067811865475f));
          op[nf * 16] = f2bf(v);
        }
      }
    }
  }
}

// ---------------- MFMA grid attention (N=256, hd=16, 4 heads) --------------
// Block = (gb, h); 4 waves, each owning 64 queries. Swapped QK^T:
//   S^T tile = mfma(A=K[m][d(pad32)], B=Q^T[d(pad32)][q]) ; col=q=lane&15,
//   row=m=(lane>>4)*4+r. Softmax reduce = local + shfl_xor(16,32).
//   PV: O^T tile = mfma(A=V^T[d][m32], B=P[m32][q]) with P bounced through
//   wave-private LDS to match the B-frag k-mapping.
__global__ __launch_bounds__(256) void gattn_k(
    const unsigned short* __restrict__ Q, int q_rs, int q_c0,
    const unsigned short* __restrict__ K, int k_rs, int k_c0,
    const unsigned short* __restrict__ V, int v_rs, int v_c0,
    const float* __restrict__ pbT, unsigned short* __restrict__ outb, int o_rs, int o_c0) {
  __shared__ __align__(16) unsigned short K_lds[256 * 16];   // [m][16d] 32B rows
  __shared__ __align__(16) unsigned short Vt[16 * 264];      // [d][264m] padded
  __shared__ __align__(16) unsigned short P_lds[4 * 64 * 40];// per-wave [64q][40m] padded
  const int gb = blockIdx.x, h = blockIdx.y, tid = threadIdx.x;
  const int lane = tid & 63, wv = tid >> 6;
  const int lr = lane & 15, lg = lane >> 4;
  const int q0 = wv * 64;

  // ---- stage K rows + V transposed ----
  {
    const unsigned short* kp = K + (size_t)(gb * 256 + tid) * k_rs + k_c0 + h * 16;
    *(uint4*)&K_lds[tid * 16]     = *(const uint4*)kp;
    *(uint4*)&K_lds[tid * 16 + 8] = *(const uint4*)(kp + 8);
    const unsigned short* vp = V + (size_t)(gb * 256 + tid) * v_rs + v_c0 + h * 16;
    uint4 va = *(const uint4*)vp;
    uint4 vb = *(const uint4*)(vp + 8);
    unsigned int w8[8] = {va.x, va.y, va.z, va.w, vb.x, vb.y, vb.z, vb.w};
#pragma unroll
    for (int w = 0; w < 8; ++w) {
      Vt[(2 * w) * 264 + tid]     = (unsigned short)(w8[w] & 0xffff);
      Vt[(2 * w + 1) * 264 + tid] = (unsigned short)(w8[w] >> 16);
    }
  }
  // ---- Q fragments (hoisted): B-frag = Q[q0+qt*16+lr][d = lg*8+i], lg<2 ----
  bf8_t bq[4];
  const bf8_t bz = {0, 0, 0, 0, 0, 0, 0, 0};
#pragma unroll
  for (int qt = 0; qt < 4; ++qt) {
    bq[qt] = bz;
    if (lg < 2)
      bq[qt] = *(const bf8_t*)(Q + (size_t)(gb * 256 + q0 + qt * 16 + lr) * q_rs + q_c0 + h * 16 + lg * 8);
  }
  __syncthreads();

  const f4_t z4 = {0.f, 0.f, 0.f, 0.f};
  f4_t oacc[4];
  float mrun[4], lrun[4];
#pragma unroll
  for (int qt = 0; qt < 4; ++qt) { oacc[qt] = z4; mrun[qt] = -3e38f; lrun[qt] = 0.0f; }

  unsigned short* Pw = &P_lds[wv * 64 * 40];

  for (int m0 = 0; m0 < 256; m0 += 32) {
    // A-frags for the two 16-key QK tiles (k = d, zero-padded beyond 16)
    bf8_t ak0 = bz, ak1 = bz;
    if (lg < 2) {
      ak0 = *(const bf8_t*)&K_lds[(m0 + lr) * 16 + lg * 8];
      ak1 = *(const bf8_t*)&K_lds[(m0 + 16 + lr) * 16 + lg * 8];
    }
    // A-frag for PV: V^T[d=lr][m = m0 + lg*8 + i]
    bf8_t av = *(const bf8_t*)&Vt[lr * 264 + m0 + lg * 8];

#pragma unroll
    for (int qt = 0; qt < 4; ++qt) {
      f4_t st0 = __builtin_amdgcn_mfma_f32_16x16x32_bf16(ak0, bq[qt], z4, 0, 0, 0);
      f4_t st1 = __builtin_amdgcn_mfma_f32_16x16x32_bf16(ak1, bq[qt], z4, 0, 0, 0);
      const float* bpm = pbT + ((size_t)(h * 256 + m0 + lg * 4) << 8) + q0 + qt * 16 + lr;
      float s0[4], s1[4];
#pragma unroll
      for (int r = 0; r < 4; ++r) {
        s0[r] = fmaf(st0[r], 0.25f, bpm[r * 256]);
        s1[r] = fmaf(st1[r], 0.25f, bpm[(16 + r) * 256]);
      }
      float cmax = fmaxf(fmaxf(fmaxf(s0[0], s0[1]), fmaxf(s0[2], s0[3])),
                         fmaxf(fmaxf(s1[0], s1[1]), fmaxf(s1[2], s1[3])));
      cmax = fmaxf(cmax, __shfl_xor(cmax, 16));
      cmax = fmaxf(cmax, __shfl_xor(cmax, 32));
      float newm = fmaxf(mrun[qt], cmax);
      float c = __expf(mrun[qt] - newm);
      float p0[4], p1[4], ls = 0.0f;
#pragma unroll
      for (int r = 0; r < 4; ++r) {
        p0[r] = __expf(s0[r] - newm);
        p1[r] = __expf(s1[r] - newm);
        ls += p0[r] + p1[r];
      }
      ls += __shfl_xor(ls, 16);
      ls += __shfl_xor(ls, 32);
      lrun[qt] = lrun[qt] * c + ls;
      mrun[qt] = newm;
#pragma unroll
      for (int r = 0; r < 4; ++r) oacc[qt][r] *= c;
      // pack P -> wave-private LDS (rows m = lg*4+r and 16+lg*4+r, col q)
      int row = qt * 16 + lr;
      uint2 w0 = {pk2(p0[0], p0[1]), pk2(p0[2], p0[3])};
      uint2 w1 = {pk2(p1[0], p1[1]), pk2(p1[2], p1[3])};
      *(uint2*)&Pw[row * 40 + lg * 4]      = w0;
      *(uint2*)&Pw[row * 40 + 16 + lg * 4] = w1;
    }
    // PV: one K=32 MFMA per q-tile
#pragma unroll
    for (int qt = 0; qt < 4; ++qt) {
      bf8_t bp = *(const bf8_t*)&Pw[(qt * 16 + lr) * 40 + lg * 8];
      oacc[qt] = __builtin_amdgcn_mfma_f32_16x16x32_bf16(av, bp, oacc[qt], 0, 0, 0);
    }
  }

  // ---- epilogue: scale by 1/l, store O^T tile (lane: q=lr, d=lg*4+r) ----
#pragma unroll
  for (int qt = 0; qt < 4; ++qt) {
    float inv = 1.0f / lrun[qt];
    uint2 o;
    o.x = pk2(oacc[qt][0] * inv, oacc[qt][1] * inv);
    o.y = pk2(oacc[qt][2] * inv, oacc[qt][3] * inv);
    unsigned short* op = outb + (size_t)(gb * 256 + q0 + qt * 16 + lr) * o_rs + o_c0 + h * 16 + lg * 4;
    *(uint2*)op = o;
  }
}

// ---------------- fused swin window attention (channel-last I/O) -----------
__global__ __launch_bounds__(256) void swin_k(
    const float* __restrict__ xTf, int c0, int shift,
    const float* __restrict__ qkvw, const float* __restrict__ qkvb,
    const float* __restrict__ rpb, const float* __restrict__ pw,
    const float* __restrict__ pb, unsigned short* __restrict__ yT, int yc0) {
  __shared__ float xt[64][33];
  __shared__ float qkvs[96][64];
  __shared__ float rps[900];
  __shared__ float ao[64][33];
  const int wb = blockIdx.x;
  const int b = wb >> 8;
  const int wrem = wb & 255;
  const int wh = wrem >> 4, ww = wrem & 15;
  const int tid = threadIdx.x;

  for (int i = tid; i < 900; i += 256) rps[i] = rpb[i];
  {
    int n = tid & 63, cg = tid >> 6;
    int r = n >> 3, c_ = n & 7;
    int hsrc = (wh * 8 + r + shift) & 127;
    int wsrc = (ww * 8 + c_ + shift) & 127;
    const float* xr = xTf + ((size_t)(b * 16384 + hsrc * 128 + wsrc)) * 128 + c0 + cg * 8;
    float4 v0 = *(const float4*)xr, v1 = *(const float4*)(xr + 4);
    xt[n][cg * 8 + 0] = v0.x; xt[n][cg * 8 + 1] = v0.y;
    xt[n][cg * 8 + 2] = v0.z; xt[n][cg * 8 + 3] = v0.w;
    xt[n][cg * 8 + 4] = v1.x; xt[n][cg * 8 + 5] = v1.y;
    xt[n][cg * 8 + 6] = v1.z; xt[n][cg * 8 + 7] = v1.w;
  }
  __syncthreads();
  {
    int n = tid & 63, cg = tid >> 6;
    for (int co = cg; co < 96; co += 4) {
      float s = qkvb[co];
      const float* wr = qkvw + co * 32;
#pragma unroll
      for (int ci = 0; ci < 32; ++ci) s = fmaf(wr[ci], xt[n][ci], s);
      qkvs[co][n] = s;
    }
  }
  __syncthreads();
  {
    const int h = tid >> 6, n = tid & 63;
    float q[8];
#pragma unroll
    for (int d = 0; d < 8; ++d) q[d] = qkvs[h * 8 + d][n] * 0.35355339059327373f;
    const int rn = n >> 3, cn = n & 7;
    int regn = 0;
    if (shift > 0) {
      int hr = wh * 8 + rn, wr_ = ww * 8 + cn;
      int rh = hr < 120 ? 0 : (hr < 124 ? 1 : 2);
      int rw = wr_ < 120 ? 0 : (wr_ < 124 ? 1 : 2);
      regn = rh * 3 + rw;
    }
    float s[64];
#pragma unroll
    for (int m = 0; m < 64; ++m) {
      float v = 0.0f;
#pragma unroll
      for (int d = 0; d < 8; ++d) v = fmaf(q[d], qkvs[32 + h * 8 + d][m], v);
      int rm = m >> 3, cm = m & 7;
      v += rps[((rn - rm + 7) * 15 + (cn - cm + 7)) * 4 + h];
      if (shift > 0) {
        int hr = wh * 8 + rm, wr_ = ww * 8 + cm;
        int rh = hr < 120 ? 0 : (hr < 124 ? 1 : 2);
        int rw = wr_ < 120 ? 0 : (wr_ < 124 ? 1 : 2);
        if (rh * 3 + rw != regn) v -= 100.0f;
      }
      s[m] = v;
    }
    float mx = -1e30f;
#pragma unroll
    for (int m = 0; m < 64; ++m) mx = fmaxf(mx, s[m]);
    float l = 0.0f;
#pragma unroll
    for (int m = 0; m < 64; ++m) {
      float p = __expf(s[m] - mx);
      s[m] = p;
      l += p;
    }
    float inv = 1.0f / l;
    float o[8];
#pragma unroll
    for (int d = 0; d < 8; ++d) o[d] = 0.0f;
#pragma unroll
    for (int m = 0; m < 64; ++m) {
      float p = s[m];
#pragma unroll
      for (int d = 0; d < 8; ++d) o[d] = fmaf(p, qkvs[64 + h * 8 + d][m], o[d]);
    }
#pragma unroll
    for (int d = 0; d < 8; ++d) ao[n][h * 8 + d] = o[d] * inv;
  }
  __syncthreads();
  {
    int n = tid & 63, cg = tid >> 6;
    int r = n >> 3, c_ = n & 7;
    int hdst = (wh * 8 + r + shift) & 127;
    int wdst = (ww * 8 + c_ + shift) & 127;
    float o8[8];
#pragma unroll
    for (int k = 0; k < 8; ++k) {
      int co = cg * 8 + k;
      float s = pb[co];
      const float* wr = pw + co * 32;
#pragma unroll
      for (int ci = 0; ci < 32; ++ci) s = fmaf(wr[ci], ao[n][ci], s);
      o8[k] = s;
    }
    uint4 pk;
    pk.x = pk2(o8[0], o8[1]); pk.y = pk2(o8[2], o8[3]);
    pk.z = pk2(o8[4], o8[5]); pk.w = pk2(o8[6], o8[7]);
    *(uint4*)(yT + ((size_t)(b * 16384 + hdst * 128 + wdst)) * 128 + yc0 + cg * 8) = pk;
  }
}

// ---------------------------------------------------------------------------
extern "C" void kernel_launch(void* const* d_in, const int* in_sizes, int n_in,
                              void* d_out, int out_size, void* d_ws, size_t ws_size,
                              hipStream_t stream) {
  (void)in_sizes; (void)n_in; (void)out_size; (void)ws_size;
  const float* x        = (const float*)d_in[0];
  const float* ln_g     = (const float*)d_in[1];
  const float* ln_b     = (const float*)d_in[2];
  const float* ga_qkv_w = (const float*)d_in[3];
  const float* ga_qkv_b = (const float*)d_in[4];
  const float* ga_gp_w  = (const float*)d_in[5];
  const float* ga_gp_b  = (const float*)d_in[6];
  const float* pos_w1   = (const float*)d_in[7];
  const float* pos_b1   = (const float*)d_in[8];
  const float* pos_w2   = (const float*)d_in[9];
  const float* pos_b2   = (const float*)d_in[10];
  const float* pos_w3   = (const float*)d_in[11];
  const float* pos_b3   = (const float*)d_in[12];
  const float* a1_pw    = (const float*)d_in[13];
  const float* a1_pb    = (const float*)d_in[14];
  const float* a2_pw    = (const float*)d_in[15];
  const float* a2_pb    = (const float*)d_in[16];
  const float* sw_qkv_w = (const float*)d_in[17];
  const float* sw_qkv_b = (const float*)d_in[18];
  const float* sw_rpb   = (const float*)d_in[19];
  const float* sw_pw    = (const float*)d_in[20];
  const float* sw_pb    = (const float*)d_in[21];
  const float* wn_qkv_w = (const float*)d_in[22];
  const float* wn_qkv_b = (const float*)d_in[23];
  const float* wn_rpb   = (const float*)d_in[24];
  const float* wn_pw    = (const float*)d_in[25];
  const float* wn_pb    = (const float*)d_in[26];
  const float* fc_w     = (const float*)d_in[27];
  const float* fc_b     = (const float*)d_in[28];
  const float* n2_g     = (const float*)d_in[29];
  const float* n2_b     = (const float*)d_in[30];
  const float* m1_w     = (const float*)d_in[31];
  const float* m1_b     = (const float*)d_in[32];
  const float* m2_w     = (const float*)d_in[33];
  const float* m2_b     = (const float*)d_in[34];
  float* out = (float*)d_out;
  char* base = (char*)d_ws;

  float*          xTf    = (float*)(base);                    // 32 MB
  unsigned short* qkvT   = (unsigned short*)(base + 32 * MB); // 24 MB
  unsigned short* xgridT = (unsigned short*)(base + 56 * MB); //  8 MB
  unsigned short* t1T    = (unsigned short*)(base + 64 * MB); //  8 MB
  unsigned short* t1pT   = (unsigned short*)(base + 72 * MB); //  8 MB
  unsigned short* yT     = (unsigned short*)(base + 80 * MB); // 16 MB
  unsigned short* x2T    = (unsigned short*)(base + 96 * MB); // 16 MB
  unsigned short* hT     = (unsigned short*)(base + 32 * MB); // alias
  float*          outT   = (float*)(base + 64 * MB);          // alias
  float*          pbT    = (float*)(base + 112 * MB);         //  1 MB
  float*          ptab   = (float*)(base + 113 * MB);

  pos_mlp_k<<<4, 256, 0, stream>>>(pos_w1, pos_b1, pos_w2, pos_b2, pos_w3, pos_b3, ptab);
  pbT_gather_k<<<1024, 256, 0, stream>>>(ptab, pbT);

  tin_k<<<dim3(256, 1, 4), 256, 0, stream>>>(x, xTf);

  gemm_k<4, 1, 1, 0, 1><<<dim3(512, 3, 1), 256, 0, stream>>>(
      xTf, 128, 0, ga_qkv_w, ga_qkv_b, nullptr, nullptr, nullptr, nullptr, qkvT, 192, 0);
  gemm_k<4, 1, 1, 0, 1><<<dim3(512, 1, 1), 256, 0, stream>>>(
      xTf, 128, 0, ga_gp_w, ga_gp_b, nullptr, nullptr, nullptr, nullptr, xgridT, 64, 0);

  gattn_k<<<dim3(256, 4), 256, 0, stream>>>(
      xgridT, 64, 0, qkvT, 192, 64, qkvT, 192, 128, pbT, t1T, 64, 0);
  gemm_k<4, 1, 0, 0, 0><<<dim3(512, 1, 1), 256, 0, stream>>>(
      t1T, 64, 0, a1_pw, a1_pb, nullptr, nullptr, nullptr, nullptr, t1pT, 64, 0);

  gattn_k<<<dim3(256, 4), 256, 0, stream>>>(
      qkvT, 192, 0, xgridT, 64, 0, t1pT, 64, 0, pbT, t1T, 64, 0);
  gemm_k<4, 1, 0, 0, 2><<<dim3(512, 1, 1), 256, 0, stream>>>(
      t1T, 64, 0, a2_pw, a2_pb, nullptr, nullptr, nullptr, nullptr, yT, 128, 64);

  swin_k<<<1024, 256, 0, stream>>>(xTf, 96, 0, wn_qkv_w, wn_qkv_b, wn_rpb, wn_pw, wn_pb, yT, 0);
  swin_k<<<1024, 256, 0, stream>>>(xTf, 64, 4, sw_qkv_w, sw_qkv_b, sw_rpb, sw_pw, sw_pb, yT, 32);

  gemm_k<8, 2, 0, 2, 0><<<dim3(512, 1, 1), 256, 0, stream>>>(
      yT, 128, 0, fc_w, fc_b, ln_g, ln_b, xTf, nullptr, x2T, 128, 0);

  gemm_k<8, 2, 0, 1, 0><<<dim3(512, 2, 1), 256, 0, stream>>>(
      x2T, 128, 0, m1_w, m1_b, nullptr, nullptr, nullptr, nullptr, hT, 256, 0);
  gemm_k<8, 4, 0, 3, 0><<<dim3(512, 1, 1), 256, 0, stream>>>(
      hT, 256, 0, m2_w, m2_b, n2_g, n2_b, xTf, x2T, outT, 128, 0);

  tout_k<<<dim3(256, 1, 4), 256, 0, stream>>>(outT, out);
}